// Round 2
// 962.099 us; speedup vs baseline: 1.0913x; 1.0913x over previous
//
#include <hip/hip_runtime.h>
#include <math.h>

// Problem constants
#define M_TOTAL 32768   // B*T = 16*2048
#define D_DIM   1024
#define K_DIM   2048

// d_out flat layout (float32 elements)
#define OUT0_OFF 0ULL           // quantized   [32768,1024]  (scratch until quantize)
#define OUT1_OFF 33554432ULL    // quant_loss  [32768,2048] (S scratch, then loss fill)
#define OUT2_OFF 100663296ULL   // nn_idx      [32768] (written as float)
#define OUT3_OFF 100696064ULL   // codebook    [2048,1024]

typedef _Float16 f16x4 __attribute__((ext_vector_type(4)));
typedef _Float16 f16x8 __attribute__((ext_vector_type(8)));
typedef float    f32x4 __attribute__((ext_vector_type(4)));

// ---------------------------------------------------------------------------
// async 16B global -> LDS (wave-uniform LDS base + lane*16)
// ---------------------------------------------------------------------------
__device__ __forceinline__ void async_copy16(void* lds, const void* g) {
    __builtin_amdgcn_global_load_lds(
        (const __attribute__((address_space(1))) unsigned int*)g,
        (__attribute__((address_space(3))) unsigned int*)lds, 16, 0, 0);
}

// ---------------------------------------------------------------------------
// Kernel 0: codebook fp32 -> (ch, cl) fp16 split.  c = ch + cl + O(2^-22)
//           Also writes the out3 passthrough copy (C is already in-register).
// ---------------------------------------------------------------------------
__global__ __launch_bounds__(256) void convcb_kernel(const float* __restrict__ C,
                                                     _Float16* __restrict__ ch,
                                                     _Float16* __restrict__ cl,
                                                     float* __restrict__ out3) {
    const int i = blockIdx.x * 256 + threadIdx.x;   // float4 index, 524288 total
    const float4 c = ((const float4*)C)[i];
    f16x4 h, l;
    h.x = (_Float16)c.x; l.x = (_Float16)(c.x - (float)h.x);
    h.y = (_Float16)c.y; l.y = (_Float16)(c.y - (float)h.y);
    h.z = (_Float16)c.z; l.z = (_Float16)(c.z - (float)h.z);
    h.w = (_Float16)c.w; l.w = (_Float16)(c.w - (float)h.w);
    ((f16x4*)ch)[i] = h;
    ((f16x4*)cl)[i] = l;
    ((float4*)out3)[i] = c;
}

// ---------------------------------------------------------------------------
// Kernel 0b: X fp32 -> fp16 (high part only; xl contribution is below the
// harness tolerance — verified in the prior session's numerics).
// Hoists the per-K-step convert VALU out of the GEMM hot loop.
// ---------------------------------------------------------------------------
__global__ __launch_bounds__(256) void convx_kernel(const float* __restrict__ X,
                                                    _Float16* __restrict__ xh) {
    const size_t i = (size_t)blockIdx.x * 256 + threadIdx.x;  // float4 idx, 8388608
    const float4 a = ((const float4*)X)[i];
    f16x4 h;
    h.x = (_Float16)a.x; h.y = (_Float16)a.y;
    h.z = (_Float16)a.z; h.w = (_Float16)a.w;
    ((f16x4*)xh)[i] = h;
}

// ---------------------------------------------------------------------------
// Kernel 1: MFMA GEMM  S[m][n] = xh[m]·ch[n] + xh[m]·cl[n]
// 128x128 tile, 4 waves each 64x64 (4x4 of 16x16x32 f16), BK=32.
// All three operands staged via global_load_lds (16B).
// LDS XOR-swizzle: 16B slot s of row r holds global slot s ^ ((r>>1)&3).
// global_load_lds writes linearly, so the swizzle is applied by permuting the
// per-lane GLOBAL source address (m173 pattern); reads XOR the same function.
// Spreads the 16-lane stride-64B fragment reads across all bank groups
// (baseline had SQ_LDS_BANK_CONFLICT = 2.5e7 from ~8-way conflicts).
// ---------------------------------------------------------------------------
__global__ __launch_bounds__(256) void gemm_kernel(const _Float16* __restrict__ XH,
                                                   const _Float16* __restrict__ CH,
                                                   const _Float16* __restrict__ CL,
                                                   float* __restrict__ S) {
    __shared__ _Float16 Ah[128 * 32];
    __shared__ _Float16 Bh[128 * 32];
    __shared__ _Float16 Bl[128 * 32];

    const int tid  = threadIdx.x;
    const int lane = tid & 63;
    const int wave = tid >> 6;
    const int n0 = blockIdx.x * 128;
    const int m0 = blockIdx.y * 128;
    const int wm = (wave & 1) * 64;
    const int wn = (wave >> 1) * 64;
    const int fr = lane & 15;       // row within 16x16 tile
    const int fq = lane >> 4;       // k-quad (16B slot)
    const int fsw = (fr >> 1) & 3;  // read-side swizzle ((row>>1)&3 == (fr>>1)&3)

    f32x4 acc[4][4];
#pragma unroll
    for (int mi = 0; mi < 4; mi++)
#pragma unroll
        for (int ni = 0; ni < 4; ni++) {
            acc[mi][ni].x = 0.f; acc[mi][ni].y = 0.f;
            acc[mi][ni].z = 0.f; acc[mi][ni].w = 0.f;
        }

    for (int k0 = 0; k0 < D_DIM; k0 += 32) {
        // ---- staging: 6 async 1KB issues per wave (2 A + 2 Bh + 2 Bl) ----
#pragma unroll
        for (int e = 0; e < 2; e++) {
            const int u   = wave * 128 + e * 64 + lane;   // 16B unit 0..511
            const int row = u >> 2;
            const int gslot = (u & 3) ^ ((row >> 1) & 3); // pre-swizzled source
            const size_t bofs = (size_t)(n0 + row) * D_DIM + k0 + gslot * 8;
            const size_t aofs = (size_t)(m0 + row) * D_DIM + k0 + gslot * 8;
            const size_t lofs = (size_t)(wave * 128 + e * 64) * 8;
            async_copy16((void*)(Ah + lofs), (const void*)(XH + aofs));
            async_copy16((void*)(Bh + lofs), (const void*)(CH + bofs));
            async_copy16((void*)(Bl + lofs), (const void*)(CL + bofs));
        }
        __syncthreads();

        // ---- fragments (swizzled slot) + MFMA ----
        f16x8 afrag[4], bhfrag[4], blfrag[4];
        const int sa = (fq ^ fsw) * 8;
#pragma unroll
        for (int t = 0; t < 4; t++) {
            afrag[t]  = *(const f16x8*)(Ah + (wm + t * 16 + fr) * 32 + sa);
            bhfrag[t] = *(const f16x8*)(Bh + (wn + t * 16 + fr) * 32 + sa);
            blfrag[t] = *(const f16x8*)(Bl + (wn + t * 16 + fr) * 32 + sa);
        }
#pragma unroll
        for (int mi = 0; mi < 4; mi++)
#pragma unroll
            for (int ni = 0; ni < 4; ni++) {
                acc[mi][ni] = __builtin_amdgcn_mfma_f32_16x16x32_f16(afrag[mi], bhfrag[ni], acc[mi][ni], 0, 0, 0);
                acc[mi][ni] = __builtin_amdgcn_mfma_f32_16x16x32_f16(afrag[mi], blfrag[ni], acc[mi][ni], 0, 0, 0);
            }
        __syncthreads();
    }

    // ---- epilogue: C/D layout col=lane&15, row=(lane>>4)*4+reg ----
#pragma unroll
    for (int mi = 0; mi < 4; mi++)
#pragma unroll
        for (int r = 0; r < 4; r++) {
            float* dst = S + (size_t)(m0 + wm + mi * 16 + fq * 4 + r) * K_DIM + n0 + wn;
#pragma unroll
            for (int ni = 0; ni < 4; ni++) dst[ni * 16 + fr] = acc[mi][ni][r];
        }
}

// ---------------------------------------------------------------------------
// Kernel 2: per-row stats. One wave per row-octet. Produces candidate lists
// (all k within MARGIN of row max), diversity (register-accumulated), entropy.
// ---------------------------------------------------------------------------
#define MARGIN 0.125f
__global__ __launch_bounds__(256) void rowstats_kernel(const float* __restrict__ S,
                                                       int* __restrict__ cnt,
                                                       int* __restrict__ cand,
                                                       float* __restrict__ div_acc,
                                                       float* __restrict__ hclust_acc) {
    __shared__ float sdiv[K_DIM];
    const int tid = threadIdx.x;
    for (int k = tid; k < K_DIM; k += 256) sdiv[k] = 0.0f;
    __syncthreads();

    const int lane = tid & 63;
    const int wave = tid >> 6;

    float dreg[32];
#pragma unroll
    for (int j = 0; j < 32; j++) dreg[j] = 0.0f;
    float ent_acc = 0.0f;

    for (int r8 = 0; r8 < 8; r8++) {
        const int row = blockIdx.x * 32 + wave * 8 + r8;
        const float* srow = S + (size_t)row * K_DIM;

        float v[32];
#pragma unroll
        for (int j = 0; j < 32; j++) v[j] = srow[lane + 64 * j];

        float m = v[0];
#pragma unroll
        for (int j = 1; j < 32; j++) m = fmaxf(m, v[j]);
        for (int off = 32; off > 0; off >>= 1) m = fmaxf(m, __shfl_xor(m, off, 64));

        // candidate extraction: everything within MARGIN of the max
        const float thresh = m - MARGIN;
#pragma unroll
        for (int j = 0; j < 32; j++) {
            if (v[j] > thresh) {
                const int slot = atomicAdd(&cnt[row], 1);
                if (slot < 8) cand[row * 8 + slot] = lane + 64 * j;
            }
        }

        // softmax pieces
        float Z = 0.0f;
#pragma unroll
        for (int j = 0; j < 32; j++) {
            v[j] = __expf(v[j] - m);
            Z += v[j];
        }
        for (int off = 32; off > 0; off >>= 1) Z += __shfl_xor(Z, off, 64);
        const float invZ = 1.0f / Z;

#pragma unroll
        for (int j = 0; j < 32; j++) {
            const float p = v[j] * invZ;
            dreg[j] += p;                          // diversity: same k across rows
            ent_acc += p * __log2f(p + 1e-8f);     // per-lane entropy partial
        }
    }

    // merge per-lane diversity into block LDS (4 waves -> 2-deep atomics)
#pragma unroll
    for (int j = 0; j < 32; j++) atomicAdd(&sdiv[lane + 64 * j], dreg[j]);
    for (int off = 32; off > 0; off >>= 1) ent_acc += __shfl_xor(ent_acc, off, 64);
    if (lane == 0) atomicAdd(hclust_acc, ent_acc);
    __syncthreads();

    for (int k = tid; k < K_DIM; k += 256) atomicAdd(&div_acc[k], sdiv[k]);
}

// ---------------------------------------------------------------------------
// Kernel 2b: fp64 argmax over candidate list. One wave per row.
// ---------------------------------------------------------------------------
__global__ __launch_bounds__(256) void refine_kernel(const float* __restrict__ X,
                                                     const float* __restrict__ C,
                                                     const int* __restrict__ cnt,
                                                     const int* __restrict__ cand,
                                                     float* __restrict__ nn_out) {
    const int tid = threadIdx.x;
    const int lane = tid & 63;
    const int wave = tid >> 6;
    const int row = blockIdx.x * 4 + wave;

    const int n = min(cnt[row], 8);
    const float* x = X + (size_t)row * D_DIM;

    float4 xv[4];
#pragma unroll
    for (int q = 0; q < 4; q++) xv[q] = *(const float4*)(x + lane * 4 + 256 * q);

    double bestv = -1.0e300;
    int besti = 0x7fffffff;
    for (int c = 0; c < n; c++) {
        const int idx = cand[row * 8 + c];
        const float* cb = C + (size_t)idx * D_DIM;
        double s = 0.0;
#pragma unroll
        for (int q = 0; q < 4; q++) {
            const float4 cv = *(const float4*)(cb + lane * 4 + 256 * q);
            s += (double)xv[q].x * cv.x + (double)xv[q].y * cv.y +
                 (double)xv[q].z * cv.z + (double)xv[q].w * cv.w;
        }
        for (int off = 32; off > 0; off >>= 1) s += __shfl_xor(s, off, 64);
        if (s > bestv || (s == bestv && idx < besti)) { bestv = s; besti = idx; }
    }
    if (lane == 0) nn_out[row] = (float)besti;
}

// ---------------------------------------------------------------------------
// Kernel 3: finalize scalar loss = h_clust - GAMMA * h_diversity
// ---------------------------------------------------------------------------
__global__ __launch_bounds__(256) void finalize_kernel(const float* __restrict__ div_acc,
                                                       const float* __restrict__ hclust_acc,
                                                       float* __restrict__ loss_out) {
    __shared__ float red[256];
    const int tid = threadIdx.x;
    float sum = 0.0f;
    for (int k = tid; k < K_DIM; k += 256) {
        const float d = div_acc[k] * (1.0f / 32768.0f);
        sum += d * __log2f(d + 1e-8f);
    }
    red[tid] = sum;
    __syncthreads();
    for (int s = 128; s > 0; s >>= 1) {
        if (tid < s) red[tid] += red[tid + s];
        __syncthreads();
    }
    if (tid == 0) {
        const float h_clust = -hclust_acc[0] * (1.0f / 32768.0f);
        const float h_div = -red[0];
        loss_out[0] = h_clust - 1.0f * h_div;   // GAMMA = 1
    }
}

// ---------------------------------------------------------------------------
// Kernel 4: broadcast loss scalar into out1 region (67,108,864 floats)
// ---------------------------------------------------------------------------
__global__ __launch_bounds__(256) void fill_kernel(float* __restrict__ out1,
                                                   const float* __restrict__ loss_ptr) {
    const float v = loss_ptr[0];
    const float4 f = make_float4(v, v, v, v);
    float4* o = (float4*)out1;
    const size_t stride = (size_t)gridDim.x * blockDim.x;
    for (size_t i = (size_t)blockIdx.x * blockDim.x + threadIdx.x; i < 16777216ULL; i += stride)
        o[i] = f;
}

// ---------------------------------------------------------------------------
// Kernel 5: quantized = normalize(center(codebook[nn_idx])). One wave per row.
// ---------------------------------------------------------------------------
__global__ __launch_bounds__(256) void quantize_kernel(const float* __restrict__ C,
                                                       const float* __restrict__ nn_f,
                                                       float* __restrict__ out0) {
    const int tid = threadIdx.x;
    const int lane = tid & 63;
    const int wave = tid >> 6;
    const int row = blockIdx.x * 4 + wave;

    const int idx = (int)nn_f[row];
    const float* c = C + (size_t)idx * D_DIM;

    float4 v[4];
    float sum = 0.0f;
#pragma unroll
    for (int q = 0; q < 4; q++) {
        v[q] = *(const float4*)(c + lane * 4 + 256 * q);
        sum += v[q].x + v[q].y + v[q].z + v[q].w;
    }
    for (int off = 32; off > 0; off >>= 1) sum += __shfl_xor(sum, off, 64);
    const float mean = sum * (1.0f / 1024.0f);

    float ss = 0.0f;
#pragma unroll
    for (int q = 0; q < 4; q++) {
        v[q].x -= mean; v[q].y -= mean; v[q].z -= mean; v[q].w -= mean;
        ss += v[q].x * v[q].x + v[q].y * v[q].y + v[q].z * v[q].z + v[q].w * v[q].w;
    }
    for (int off = 32; off > 0; off >>= 1) ss += __shfl_xor(ss, off, 64);
    const float inv = 1.0f / sqrtf(ss);

    float* o = out0 + (size_t)row * D_DIM;
#pragma unroll
    for (int q = 0; q < 4; q++) {
        float4 w = v[q];
        w.x *= inv; w.y *= inv; w.z *= inv; w.w *= inv;
        *(float4*)(o + lane * 4 + 256 * q) = w;
    }
}

// ---------------------------------------------------------------------------
extern "C" void kernel_launch(void* const* d_in, const int* in_sizes, int n_in,
                              void* d_out, int out_size, void* d_ws, size_t ws_size,
                              hipStream_t stream) {
    const float* X = (const float*)d_in[0];   // [16,2048,1024]
    const float* C = (const float*)d_in[1];   // [2048,1024]
    float* out = (float*)d_out;

    // scratch lives in the out0 region (free until quantize_kernel runs)
    char* scratch = (char*)d_out;
    _Float16* CH  = (_Float16*)(scratch);                 // 4 MB
    _Float16* CL  = (_Float16*)(scratch + (4 << 20));     // 4 MB
    int* cand     = (int*)(scratch + (8 << 20));          // 1 MB  [32768][8]
    int* cnt      = (int*)(scratch + (9 << 20));          // 128 KB
    float* div_acc   = (float*)(scratch + (9 << 20) + (128 << 10));  // 8 KB
    float* hclust    = div_acc + 2048;
    float* loss      = div_acc + 2049;
    _Float16* XH  = (_Float16*)(scratch + (16 << 20));    // 64 MB  [32768][1024] fp16

    float* S = out + OUT1_OFF;                // similarity scratch in out1 region

    // zero cnt + div + hclust (+loss)
    hipMemsetAsync(scratch + (9 << 20), 0, (128 << 10) + 8192 + 16, stream);

    // 0) codebook fp16 split + out3 passthrough
    convcb_kernel<<<2048, 256, 0, stream>>>(C, CH, CL, out + OUT3_OFF);

    // 0b) X fp16 convert (hoists per-K-step convert VALU out of GEMM)
    convx_kernel<<<32768, 256, 0, stream>>>(X, XH);

    // 1) S = xh·ch + xh·cl  (fp16 MFMA, all-async staging, swizzled LDS)
    gemm_kernel<<<dim3(K_DIM / 128, M_TOTAL / 128), 256, 0, stream>>>(XH, CH, CL, S);

    // 2) per-row stats -> candidates, diversity, entropy sum
    rowstats_kernel<<<M_TOTAL / 32, 256, 0, stream>>>(S, cnt, cand, div_acc, hclust);

    // 2b) fp64 argmax refinement -> nn_idx (as float)
    refine_kernel<<<M_TOTAL / 4, 256, 0, stream>>>(X, C, cnt, cand, out + OUT2_OFF);

    // 3) scalar loss
    finalize_kernel<<<1, 256, 0, stream>>>(div_acc, hclust, loss);

    // 4) broadcast loss over out1 (overwrites S scratch; S no longer needed)
    fill_kernel<<<8192, 256, 0, stream>>>(out + OUT1_OFF, loss);

    // 5) quantized rows (overwrites out0 scratch; loss already consumed)
    quantize_kernel<<<M_TOTAL / 4, 256, 0, stream>>>(C, out + OUT2_OFF, out + OUT0_OFF);
}

// Round 3
// 958.889 us; speedup vs baseline: 1.0949x; 1.0033x over previous
//
#include <hip/hip_runtime.h>
#include <math.h>

// Problem constants
#define M_TOTAL 32768   // B*T = 16*2048
#define D_DIM   1024
#define K_DIM   2048

// d_out flat layout (float32 elements)
#define OUT0_OFF 0ULL           // quantized   [32768,1024]  (scratch until refineq)
#define OUT1_OFF 33554432ULL    // quant_loss  [32768,2048] (S scratch, then loss fill)
#define OUT2_OFF 100663296ULL   // nn_idx      [32768] (written as float)
#define OUT3_OFF 100696064ULL   // codebook    [2048,1024] (cand/cnt/div scratch until tail copy)

typedef _Float16 f16x4 __attribute__((ext_vector_type(4)));
typedef _Float16 f16x8 __attribute__((ext_vector_type(8)));
typedef float    f32x4 __attribute__((ext_vector_type(4)));

#define STR_(x) #x
#define STR(x) STR_(x)
#define WAITVM(N) asm volatile("s_waitcnt vmcnt(" STR(N) ")" ::: "memory")

// ---------------------------------------------------------------------------
// async 16B global -> LDS (wave-uniform LDS base + lane*16)
// ---------------------------------------------------------------------------
__device__ __forceinline__ void async_copy16(void* lds, const void* g) {
    __builtin_amdgcn_global_load_lds(
        (const __attribute__((address_space(1))) unsigned int*)g,
        (__attribute__((address_space(3))) unsigned int*)lds, 16, 0, 0);
}

// ---------------------------------------------------------------------------
// Kernel 0: codebook fp32 -> (ch, cl) fp16 split.  c = ch + cl + O(2^-22)
// ---------------------------------------------------------------------------
__global__ __launch_bounds__(256) void convcb_kernel(const float* __restrict__ C,
                                                     _Float16* __restrict__ ch,
                                                     _Float16* __restrict__ cl) {
    const int i = blockIdx.x * 256 + threadIdx.x;   // float4 index, 524288 total
    const float4 c = ((const float4*)C)[i];
    f16x4 h, l;
    h.x = (_Float16)c.x; l.x = (_Float16)(c.x - (float)h.x);
    h.y = (_Float16)c.y; l.y = (_Float16)(c.y - (float)h.y);
    h.z = (_Float16)c.z; l.z = (_Float16)(c.z - (float)h.z);
    h.w = (_Float16)c.w; l.w = (_Float16)(c.w - (float)h.w);
    ((f16x4*)ch)[i] = h;
    ((f16x4*)cl)[i] = l;
}

// ---------------------------------------------------------------------------
// Kernel 0b: X fp32 -> fp16 (high part only; verified numerics)
// ---------------------------------------------------------------------------
__global__ __launch_bounds__(256) void convx_kernel(const float* __restrict__ X,
                                                    _Float16* __restrict__ xh) {
    const size_t i = (size_t)blockIdx.x * 256 + threadIdx.x;  // float4 idx, 8388608
    const float4 a = ((const float4*)X)[i];
    f16x4 h;
    h.x = (_Float16)a.x; h.y = (_Float16)a.y;
    h.z = (_Float16)a.z; h.w = (_Float16)a.w;
    ((f16x4*)xh)[i] = h;
}

// ---------------------------------------------------------------------------
// Kernel 1: MFMA GEMM  S[m][n] = xh[m]·ch[n] + xh[m]·cl[n]
// 8-phase counted-vmcnt schedule (T3+T4+T5):
//   tile 256x128, BK=64, 8 waves (4M x 2N, each 64x64), LDS 128KB dbuf.
//   4 phases per K-tile: {A·Bh k0, A·Bl k0, A·Bh k1, A·Bl k1}, 16 MFMA each.
//   Prefetch chunks c0..c3 = {A-k0+Bh-k0 (3 ld/thr)}, {Bl-k0 (1)}, {A-k1+Bh-k1 (3)},
//   {Bl-k1 (1)} issued one-per-phase for tile t+1; waits vmcnt(7)/(5)/(7)/(5)
//   drain exactly the chunk the NEXT phase reads. Never vmcnt(0) in steady loop.
//   Raw s_barrier (NOT __syncthreads -- that would re-insert the vmcnt(0) drain).
// LDS layout per operand: [kh][row][4 units of 16B], unit XOR fq^(row&3):
//   chunks are LDS-contiguous (global_load_lds linear-fill constraint) and
//   ds_read_b128 stays bank-uniform. Global source carries the permutation.
// ---------------------------------------------------------------------------
__device__ __forceinline__ void loadA4(f16x8* a, const _Float16* Ab, int wm, int fr, int fq, int kh) {
#pragma unroll
    for (int mi = 0; mi < 4; mi++) {
        const int row = wm + mi * 16 + fr;
        a[mi] = *(const f16x8*)(Ab + kh * 8192 + row * 32 + (fq ^ (row & 3)) * 8);
    }
}
__device__ __forceinline__ void loadB4(f16x8* b, const _Float16* Bb, int wn, int fr, int fq, int kh) {
#pragma unroll
    for (int ni = 0; ni < 4; ni++) {
        const int row = wn + ni * 16 + fr;
        b[ni] = *(const f16x8*)(Bb + kh * 4096 + row * 32 + (fq ^ (row & 3)) * 8);
    }
}

__global__ __launch_bounds__(512) void gemm_kernel(const _Float16* __restrict__ XH,
                                                   const _Float16* __restrict__ CH,
                                                   const _Float16* __restrict__ CL,
                                                   float* __restrict__ S) {
    __shared__ _Float16 lds[65536];      // 128 KB
    _Float16* const A0  = lds;           // [2][256][32]  (kh-major)
    _Float16* const Bh0 = lds + 16384;   // [2][128][32]
    _Float16* const Bl0 = lds + 24576;
    _Float16* const A1  = lds + 32768;
    _Float16* const Bh1 = lds + 49152;
    _Float16* const Bl1 = lds + 57344;

    const int tid  = threadIdx.x;
    const int lane = tid & 63;
    const int wave = tid >> 6;

    // XCD-grouped mapping: xcd x owns m-blocks [x*16, x*16+16) x all 16 n-blocks
    const int bq  = blockIdx.x;
    const int xcd = bq & 7;
    const int idx = bq >> 3;
    const int m0 = (xcd * 16 + (idx >> 4)) * 256;
    const int n0 = (idx & 15) * 128;

    const int wm = (wave & 3) * 64;      // 4 M-waves
    const int wn = (wave >> 2) * 64;     // 2 N-waves
    const int fr = lane & 15;
    const int fq = lane >> 4;

    // ---- staging constants (per-thread, hoisted out of the K loop) ----
    size_t aoff[2][2]; int alds[2][2];
#pragma unroll
    for (int e = 0; e < 2; e++) {
        const int U = (wave * 2 + e) * 64 + lane;
        const int row = U >> 2;
#pragma unroll
        for (int kh = 0; kh < 2; kh++) {
            aoff[e][kh] = (size_t)(m0 + row) * D_DIM + (size_t)(kh * 4 + ((U & 3) ^ (row & 3))) * 8;
            alds[e][kh] = kh * 8192 + (wave * 2 + e) * 512;
        }
    }
    size_t boff[2]; int blds[2];
    {
        const int U = wave * 64 + lane;
        const int row = U >> 2;
#pragma unroll
        for (int kh = 0; kh < 2; kh++) {
            boff[kh] = (size_t)(n0 + row) * D_DIM + (size_t)(kh * 4 + ((U & 3) ^ (row & 3))) * 8;
            blds[kh] = kh * 4096 + wave * 512;
        }
    }

#define STAGE_A(Abuf, KH, kb) do {                                                        \
    async_copy16((void*)((Abuf) + alds[0][KH]), (const void*)(XH + aoff[0][KH] + (kb)));  \
    async_copy16((void*)((Abuf) + alds[1][KH]), (const void*)(XH + aoff[1][KH] + (kb)));  \
} while (0)
#define STAGE_BH(Bbuf, KH, kb) async_copy16((void*)((Bbuf) + blds[KH]), (const void*)(CH + boff[KH] + (kb)))
#define STAGE_BL(Bbuf, KH, kb) async_copy16((void*)((Bbuf) + blds[KH]), (const void*)(CL + boff[KH] + (kb)))

#define PH_MFMA() do {                                                                    \
    __builtin_amdgcn_s_barrier();                                                         \
    asm volatile("s_waitcnt lgkmcnt(0)" ::: "memory");                                    \
    __builtin_amdgcn_sched_barrier(0);                                                    \
    __builtin_amdgcn_s_setprio(1);                                                        \
    _Pragma("unroll")                                                                     \
    for (int mi = 0; mi < 4; mi++) {                                                      \
        _Pragma("unroll")                                                                 \
        for (int ni = 0; ni < 4; ni++)                                                    \
            acc[mi][ni] = __builtin_amdgcn_mfma_f32_16x16x32_f16(a[mi], b[ni], acc[mi][ni], 0, 0, 0); \
    }                                                                                     \
    __builtin_amdgcn_s_setprio(0);                                                        \
    __builtin_amdgcn_s_barrier();                                                         \
} while (0)

    f32x4 acc[4][4];
#pragma unroll
    for (int mi = 0; mi < 4; mi++)
#pragma unroll
        for (int ni = 0; ni < 4; ni++) {
            acc[mi][ni].x = 0.f; acc[mi][ni].y = 0.f;
            acc[mi][ni].z = 0.f; acc[mi][ni].w = 0.f;
        }

    f16x8 a[4], b[4];

    // ---- prologue: stage tile 0 (chunks c0..c3 in vmcnt FIFO order) ----
    STAGE_A(A0, 0, 0); STAGE_BH(Bh0, 0, 0);   // c0 (3 loads/thread)
    STAGE_BL(Bl0, 0, 0);                      // c1 (1)
    STAGE_A(A0, 1, 0); STAGE_BH(Bh0, 1, 0);   // c2 (3)
    STAGE_BL(Bl0, 1, 0);                      // c3 (1)
    WAITVM(5);                                // c0 complete
    __builtin_amdgcn_s_barrier();

    // ---- steady loop: tiles 0..14 prefetch tile t+1 ----
    for (int t = 0; t < 15; t++) {
        _Float16* const Ac  = (t & 1) ? A1 : A0;
        _Float16* const Bhc = (t & 1) ? Bh1 : Bh0;
        _Float16* const Blc = (t & 1) ? Bl1 : Bl0;
        _Float16* const An  = (t & 1) ? A0 : A1;
        _Float16* const Bhn = (t & 1) ? Bh0 : Bh1;
        _Float16* const Bln = (t & 1) ? Bl0 : Bl1;
        const size_t kb = (size_t)(t + 1) * 64;

        // phase 0: A·Bh k0   (issue t+1.c0; drain t.c1 for phase 1)
        loadA4(a, Ac, wm, fr, fq, 0);
        loadB4(b, Bhc, wn, fr, fq, 0);
        STAGE_A(An, 0, kb); STAGE_BH(Bhn, 0, kb);
        WAITVM(7);
        PH_MFMA();
        // phase 1: A·Bl k0   (issue t+1.c1; drain t.c2 for phase 2)
        loadB4(b, Blc, wn, fr, fq, 0);
        STAGE_BL(Bln, 0, kb);
        WAITVM(5);
        PH_MFMA();
        // phase 2: A·Bh k1   (issue t+1.c2; drain t.c3 for phase 3)
        loadA4(a, Ac, wm, fr, fq, 1);
        loadB4(b, Bhc, wn, fr, fq, 1);
        STAGE_A(An, 1, kb); STAGE_BH(Bhn, 1, kb);
        WAITVM(7);
        PH_MFMA();
        // phase 3: A·Bl k1   (issue t+1.c3; drain t+1.c0 for next tile's phase 0)
        loadB4(b, Blc, wn, fr, fq, 1);
        STAGE_BL(Bln, 1, kb);
        WAITVM(5);
        PH_MFMA();
    }

    // ---- final tile t=15 (buffers *1, no prefetch; waits drain own chunks) ----
    loadA4(a, A1, wm, fr, fq, 0);
    loadB4(b, Bh1, wn, fr, fq, 0);
    WAITVM(4);                       // c1 done
    PH_MFMA();
    loadB4(b, Bl1, wn, fr, fq, 0);
    WAITVM(1);                       // c2 done
    PH_MFMA();
    loadA4(a, A1, wm, fr, fq, 1);
    loadB4(b, Bh1, wn, fr, fq, 1);
    WAITVM(0);                       // c3 done (only drain-to-0, once, at the end)
    PH_MFMA();
    loadB4(b, Bl1, wn, fr, fq, 1);
    __builtin_amdgcn_s_barrier();
    asm volatile("s_waitcnt lgkmcnt(0)" ::: "memory");
    __builtin_amdgcn_sched_barrier(0);
#pragma unroll
    for (int mi = 0; mi < 4; mi++)
#pragma unroll
        for (int ni = 0; ni < 4; ni++)
            acc[mi][ni] = __builtin_amdgcn_mfma_f32_16x16x32_f16(a[mi], b[ni], acc[mi][ni], 0, 0, 0);

    // ---- epilogue: C/D layout col=lane&15, row=(lane>>4)*4+reg ----
#pragma unroll
    for (int mi = 0; mi < 4; mi++)
#pragma unroll
        for (int r = 0; r < 4; r++) {
            float* dst = S + (size_t)(m0 + wm + mi * 16 + fq * 4 + r) * K_DIM + n0 + wn;
#pragma unroll
            for (int ni = 0; ni < 4; ni++) dst[ni * 16 + fr] = acc[mi][ni][r];
        }
#undef STAGE_A
#undef STAGE_BH
#undef STAGE_BL
#undef PH_MFMA
}

// ---------------------------------------------------------------------------
// Kernel 2: per-row stats (float4 S loads). One wave per row-octet.
// k index of (q,e) lane-element: k = q*256 + lane*4 + e.
// ---------------------------------------------------------------------------
#define MARGIN 0.125f
__global__ __launch_bounds__(256) void rowstats_kernel(const float* __restrict__ S,
                                                       int* __restrict__ cnt,
                                                       int* __restrict__ cand,
                                                       float* __restrict__ div_acc,
                                                       float* __restrict__ hclust_acc) {
    __shared__ float sdiv[K_DIM];
    const int tid = threadIdx.x;
    for (int k = tid; k < K_DIM; k += 256) sdiv[k] = 0.0f;
    __syncthreads();

    const int lane = tid & 63;
    const int wave = tid >> 6;

    float dreg[32];
#pragma unroll
    for (int j = 0; j < 32; j++) dreg[j] = 0.0f;
    float ent_acc = 0.0f;

    for (int r8 = 0; r8 < 8; r8++) {
        const int row = blockIdx.x * 32 + wave * 8 + r8;
        const float* srow = S + (size_t)row * K_DIM;

        float v[32];
#pragma unroll
        for (int q = 0; q < 8; q++) {
            const float4 t4 = ((const float4*)srow)[q * 64 + lane];
            v[q * 4 + 0] = t4.x; v[q * 4 + 1] = t4.y;
            v[q * 4 + 2] = t4.z; v[q * 4 + 3] = t4.w;
        }

        float m = v[0];
#pragma unroll
        for (int j = 1; j < 32; j++) m = fmaxf(m, v[j]);
        for (int off = 32; off > 0; off >>= 1) m = fmaxf(m, __shfl_xor(m, off, 64));

        // candidate extraction: everything within MARGIN of the max
        const float thresh = m - MARGIN;
#pragma unroll
        for (int j = 0; j < 32; j++) {
            if (v[j] > thresh) {
                const int slot = atomicAdd(&cnt[row], 1);
                if (slot < 8) cand[row * 8 + slot] = (j >> 2) * 256 + lane * 4 + (j & 3);
            }
        }

        // softmax pieces
        float Z = 0.0f;
#pragma unroll
        for (int j = 0; j < 32; j++) {
            v[j] = __expf(v[j] - m);
            Z += v[j];
        }
        for (int off = 32; off > 0; off >>= 1) Z += __shfl_xor(Z, off, 64);
        const float invZ = 1.0f / Z;

#pragma unroll
        for (int j = 0; j < 32; j++) {
            const float p = v[j] * invZ;
            dreg[j] += p;
            ent_acc += p * __log2f(p + 1e-8f);
        }
    }

    // merge per-lane diversity into block LDS, then global
#pragma unroll
    for (int j = 0; j < 32; j++)
        atomicAdd(&sdiv[(j >> 2) * 256 + lane * 4 + (j & 3)], dreg[j]);
    for (int off = 32; off > 0; off >>= 1) ent_acc += __shfl_xor(ent_acc, off, 64);
    if (lane == 0) atomicAdd(hclust_acc, ent_acc);
    __syncthreads();

    for (int k = tid; k < K_DIM; k += 256) atomicAdd(&div_acc[k], sdiv[k]);
}

// ---------------------------------------------------------------------------
// Kernel 2b: fp64 argmax over candidate list + fused quantize. One wave/row.
// After the reduce every lane holds the same besti, so the quantize step
// (center+normalize codebook[besti]) runs in-wave; C row is L2-hot.
// ---------------------------------------------------------------------------
__global__ __launch_bounds__(256) void refineq_kernel(const float* __restrict__ X,
                                                      const float* __restrict__ C,
                                                      const int* __restrict__ cnt,
                                                      const int* __restrict__ cand,
                                                      float* __restrict__ nn_out,
                                                      float* __restrict__ out0) {
    const int tid = threadIdx.x;
    const int lane = tid & 63;
    const int wave = tid >> 6;
    const int row = blockIdx.x * 4 + wave;

    const int n = min(cnt[row], 8);
    const float* x = X + (size_t)row * D_DIM;

    float4 xv[4];
#pragma unroll
    for (int q = 0; q < 4; q++) xv[q] = *(const float4*)(x + lane * 4 + 256 * q);

    double bestv = -1.0e300;
    int besti = 0x7fffffff;
    for (int c = 0; c < n; c++) {
        const int idx = cand[row * 8 + c];
        const float* cb = C + (size_t)idx * D_DIM;
        double s = 0.0;
#pragma unroll
        for (int q = 0; q < 4; q++) {
            const float4 cv = *(const float4*)(cb + lane * 4 + 256 * q);
            s += (double)xv[q].x * cv.x + (double)xv[q].y * cv.y +
                 (double)xv[q].z * cv.z + (double)xv[q].w * cv.w;
        }
        for (int off = 32; off > 0; off >>= 1) s += __shfl_xor(s, off, 64);
        if (s > bestv || (s == bestv && idx < besti)) { bestv = s; besti = idx; }
    }
    if (lane == 0) nn_out[row] = (float)besti;

    // ---- fused quantize: normalize(center(C[besti])) ----
    const float* c = C + (size_t)besti * D_DIM;
    float4 v[4];
    float sum = 0.0f;
#pragma unroll
    for (int q = 0; q < 4; q++) {
        v[q] = *(const float4*)(c + lane * 4 + 256 * q);
        sum += v[q].x + v[q].y + v[q].z + v[q].w;
    }
    for (int off = 32; off > 0; off >>= 1) sum += __shfl_xor(sum, off, 64);
    const float mean = sum * (1.0f / 1024.0f);

    float ss = 0.0f;
#pragma unroll
    for (int q = 0; q < 4; q++) {
        v[q].x -= mean; v[q].y -= mean; v[q].z -= mean; v[q].w -= mean;
        ss += v[q].x * v[q].x + v[q].y * v[q].y + v[q].z * v[q].z + v[q].w * v[q].w;
    }
    for (int off = 32; off > 0; off >>= 1) ss += __shfl_xor(ss, off, 64);
    const float inv = 1.0f / sqrtf(ss);

    float* o = out0 + (size_t)row * D_DIM;
#pragma unroll
    for (int q = 0; q < 4; q++) {
        float4 w = v[q];
        w.x *= inv; w.y *= inv; w.z *= inv; w.w *= inv;
        *(float4*)(o + lane * 4 + 256 * q) = w;
    }
}

// ---------------------------------------------------------------------------
// Kernel 3: finalize scalar loss = h_clust - GAMMA * h_diversity
// ---------------------------------------------------------------------------
__global__ __launch_bounds__(256) void finalize_kernel(const float* __restrict__ div_acc,
                                                       const float* __restrict__ hclust_acc,
                                                       float* __restrict__ loss_out) {
    __shared__ float red[256];
    const int tid = threadIdx.x;
    float sum = 0.0f;
    for (int k = tid; k < K_DIM; k += 256) {
        const float d = div_acc[k] * (1.0f / 32768.0f);
        sum += d * __log2f(d + 1e-8f);
    }
    red[tid] = sum;
    __syncthreads();
    for (int s = 128; s > 0; s >>= 1) {
        if (tid < s) red[tid] += red[tid + s];
        __syncthreads();
    }
    if (tid == 0) {
        const float h_clust = -hclust_acc[0] * (1.0f / 32768.0f);
        const float h_div = -red[0];
        loss_out[0] = h_clust - 1.0f * h_div;   // GAMMA = 1
    }
}

// ---------------------------------------------------------------------------
// Kernel 4: broadcast loss scalar into out1 region (67,108,864 floats)
// ---------------------------------------------------------------------------
__global__ __launch_bounds__(256) void fill_kernel(float* __restrict__ out1,
                                                   const float* __restrict__ loss_ptr) {
    const float v = loss_ptr[0];
    const float4 f = make_float4(v, v, v, v);
    float4* o = (float4*)out1;
    const size_t stride = (size_t)gridDim.x * blockDim.x;
    for (size_t i = (size_t)blockIdx.x * blockDim.x + threadIdx.x; i < 16777216ULL; i += stride)
        o[i] = f;
}

// ---------------------------------------------------------------------------
// Kernel 6: codebook passthrough copy (runs LAST: out3 region holds scratch
// cand/cnt/div until then)
// ---------------------------------------------------------------------------
__global__ __launch_bounds__(256) void copycb_kernel(const float* __restrict__ C,
                                                     float* __restrict__ out3) {
    const size_t i = (size_t)blockIdx.x * 256 + threadIdx.x;
    if (i < 524288ULL) ((float4*)out3)[i] = ((const float4*)C)[i];
}

// ---------------------------------------------------------------------------
extern "C" void kernel_launch(void* const* d_in, const int* in_sizes, int n_in,
                              void* d_out, int out_size, void* d_ws, size_t ws_size,
                              hipStream_t stream) {
    const float* X = (const float*)d_in[0];   // [16,2048,1024]
    const float* C = (const float*)d_in[1];   // [2048,1024]
    float* out = (float*)d_out;

    // fp16 operand scratch in the out0 region (free until refineq writes out0)
    char* scratch = (char*)d_out;
    _Float16* CH  = (_Float16*)(scratch);                 // 4 MB
    _Float16* CL  = (_Float16*)(scratch + (4 << 20));     // 4 MB
    _Float16* XH  = (_Float16*)(scratch + (16 << 20));    // 64 MB  [32768][1024] fp16

    // cand/cnt/div scratch in the out3 region (free until tail copycb;
    // survives refineq's out0 writes)
    char* s3 = (char*)(out + OUT3_OFF);
    int* cand      = (int*)s3;                            // 1 MB   [32768][8]
    int* cnt       = (int*)(s3 + (1 << 20));              // 128 KB
    float* div_acc = (float*)(s3 + (1 << 20) + (128 << 10));  // 8 KB
    float* hclust  = div_acc + 2048;
    float* loss    = div_acc + 2049;

    float* S = out + OUT1_OFF;                // similarity scratch in out1 region

    // zero cnt + div + hclust + loss (contiguous)
    hipMemsetAsync(s3 + (1 << 20), 0, (128 << 10) + 8192 + 16, stream);

    // 0) codebook fp16 split
    convcb_kernel<<<2048, 256, 0, stream>>>(C, CH, CL);

    // 0b) X fp16 convert
    convx_kernel<<<32768, 256, 0, stream>>>(X, XH);

    // 1) S = xh·ch + xh·cl  (8-phase counted-vmcnt MFMA GEMM)
    gemm_kernel<<<2048, 512, 0, stream>>>(XH, CH, CL, S);

    // 2) per-row stats -> candidates, diversity, entropy sum
    rowstats_kernel<<<M_TOTAL / 32, 256, 0, stream>>>(S, cnt, cand, div_acc, hclust);

    // 2b) fp64 argmax refinement + fused quantize -> nn_idx, out0
    refineq_kernel<<<M_TOTAL / 4, 256, 0, stream>>>(X, C, cnt, cand,
                                                    out + OUT2_OFF, out + OUT0_OFF);

    // 3) scalar loss
    finalize_kernel<<<1, 256, 0, stream>>>(div_acc, hclust, loss);

    // 4) broadcast loss over out1 (overwrites S scratch)
    fill_kernel<<<8192, 256, 0, stream>>>(out + OUT1_OFF, loss);

    // 6) codebook copy (frees nothing -- just the real out3 payload, last)
    copycb_kernel<<<2048, 256, 0, stream>>>(C, out + OUT3_OFF);
}

// Round 4
// 951.831 us; speedup vs baseline: 1.1031x; 1.0074x over previous
//
#include <hip/hip_runtime.h>
#include <math.h>

// Problem constants
#define M_TOTAL 32768   // B*T = 16*2048
#define D_DIM   1024
#define K_DIM   2048

// d_out flat layout (float32 elements)
#define OUT0_OFF 0ULL           // quantized   [32768,1024]  (scratch until refineq)
#define OUT1_OFF 33554432ULL    // quant_loss  [32768,2048] (S scratch, then loss fill)
#define OUT2_OFF 100663296ULL   // nn_idx      [32768] (written as float)
#define OUT3_OFF 100696064ULL   // codebook    [2048,1024] (cand/cnt/div scratch until tail copy)

typedef _Float16 f16x4 __attribute__((ext_vector_type(4)));
typedef _Float16 f16x8 __attribute__((ext_vector_type(8)));
typedef float    f32x4 __attribute__((ext_vector_type(4)));

#define STR_(x) #x
#define STR(x) STR_(x)
#define WAITVM(N) asm volatile("s_waitcnt vmcnt(" STR(N) ")" ::: "memory")

// ---------------------------------------------------------------------------
// async 16B global -> LDS (wave-uniform LDS base + lane*16)
// ---------------------------------------------------------------------------
__device__ __forceinline__ void async_copy16(void* lds, const void* g) {
    __builtin_amdgcn_global_load_lds(
        (const __attribute__((address_space(1))) unsigned int*)g,
        (__attribute__((address_space(3))) unsigned int*)lds, 16, 0, 0);
}

// ---------------------------------------------------------------------------
// Kernel 0: codebook fp32 -> (ch, cl) fp16 split.  c = ch + cl + O(2^-22)
// ---------------------------------------------------------------------------
__global__ __launch_bounds__(256) void convcb_kernel(const float* __restrict__ C,
                                                     _Float16* __restrict__ ch,
                                                     _Float16* __restrict__ cl) {
    const int i = blockIdx.x * 256 + threadIdx.x;   // float4 index, 524288 total
    const float4 c = ((const float4*)C)[i];
    f16x4 h, l;
    h.x = (_Float16)c.x; l.x = (_Float16)(c.x - (float)h.x);
    h.y = (_Float16)c.y; l.y = (_Float16)(c.y - (float)h.y);
    h.z = (_Float16)c.z; l.z = (_Float16)(c.z - (float)h.z);
    h.w = (_Float16)c.w; l.w = (_Float16)(c.w - (float)h.w);
    ((f16x4*)ch)[i] = h;
    ((f16x4*)cl)[i] = l;
}

// ---------------------------------------------------------------------------
// Kernel 0b: X fp32 -> fp16 (high part only; verified numerics)
// ---------------------------------------------------------------------------
__global__ __launch_bounds__(256) void convx_kernel(const float* __restrict__ X,
                                                    _Float16* __restrict__ xh) {
    const size_t i = (size_t)blockIdx.x * 256 + threadIdx.x;  // float4 idx, 8388608
    const float4 a = ((const float4*)X)[i];
    f16x4 h;
    h.x = (_Float16)a.x; h.y = (_Float16)a.y;
    h.z = (_Float16)a.z; h.w = (_Float16)a.w;
    ((f16x4*)xh)[i] = h;
}

// ---------------------------------------------------------------------------
// Kernel 1: MFMA GEMM  S[m][n] = xh[m]·ch[n] + xh[m]·cl[n]
// 8-phase counted-vmcnt schedule (T3+T4+T5):
//   tile 256x128, BK=64, 8 waves (4M x 2N, each 64x64), LDS 128KB dbuf.
//   4 phases per K-tile: {A·Bh k0, A·Bl k0, A·Bh k1, A·Bl k1}, 16 MFMA each.
//   Prefetch chunks c0..c3 = {A-k0+Bh-k0 (3 ld/thr)}, {Bl-k0 (1)}, {A-k1+Bh-k1 (3)},
//   {Bl-k1 (1)} issued one-per-phase for tile t+1; waits vmcnt(7)/(5)/(7)/(5)
//   drain exactly the chunk the NEXT phase reads. Never vmcnt(0) in steady loop.
//   Raw s_barrier (NOT __syncthreads -- that would re-insert the vmcnt(0) drain).
// LDS layout per operand: [kh][row][4 units of 16B], unit XOR fq^((row>>1)&3).
//   (row>>1)&3 -- NOT row&3: for a quarter-wave b128 phase (fq fixed, fr=0..15)
//   the 16B-group is 4*(fr&1) + (fq^swz); (fr>>1)&3 covers all 8 groups exactly
//   twice (free); fr&3 covers only 4 groups -> 4-way conflict (R3's 2.5e7).
//   Chunks stay LDS-contiguous (global_load_lds linear-fill constraint); the
//   global source address carries the permutation (involution both sides).
// ---------------------------------------------------------------------------
__device__ __forceinline__ void loadA4(f16x8* a, const _Float16* Ab, int wm, int fr, int fq, int kh) {
#pragma unroll
    for (int mi = 0; mi < 4; mi++) {
        const int row = wm + mi * 16 + fr;
        a[mi] = *(const f16x8*)(Ab + kh * 8192 + row * 32 + (fq ^ ((row >> 1) & 3)) * 8);
    }
}
__device__ __forceinline__ void loadB4(f16x8* b, const _Float16* Bb, int wn, int fr, int fq, int kh) {
#pragma unroll
    for (int ni = 0; ni < 4; ni++) {
        const int row = wn + ni * 16 + fr;
        b[ni] = *(const f16x8*)(Bb + kh * 4096 + row * 32 + (fq ^ ((row >> 1) & 3)) * 8);
    }
}

__global__ __launch_bounds__(512) void gemm_kernel(const _Float16* __restrict__ XH,
                                                   const _Float16* __restrict__ CH,
                                                   const _Float16* __restrict__ CL,
                                                   float* __restrict__ S) {
    __shared__ _Float16 lds[65536];      // 128 KB
    _Float16* const A0  = lds;           // [2][256][32]  (kh-major)
    _Float16* const Bh0 = lds + 16384;   // [2][128][32]
    _Float16* const Bl0 = lds + 24576;
    _Float16* const A1  = lds + 32768;
    _Float16* const Bh1 = lds + 49152;
    _Float16* const Bl1 = lds + 57344;

    const int tid  = threadIdx.x;
    const int lane = tid & 63;
    const int wave = tid >> 6;

    // XCD-grouped mapping: xcd x owns m-blocks [x*16, x*16+16) x all 16 n-blocks
    const int bq  = blockIdx.x;
    const int xcd = bq & 7;
    const int idx = bq >> 3;
    const int m0 = (xcd * 16 + (idx >> 4)) * 256;
    const int n0 = (idx & 15) * 128;

    const int wm = (wave & 3) * 64;      // 4 M-waves
    const int wn = (wave >> 2) * 64;     // 2 N-waves
    const int fr = lane & 15;
    const int fq = lane >> 4;

    // ---- staging constants (per-thread, hoisted out of the K loop) ----
    size_t aoff[2][2]; int alds[2][2];
#pragma unroll
    for (int e = 0; e < 2; e++) {
        const int U = (wave * 2 + e) * 64 + lane;
        const int row = U >> 2;
#pragma unroll
        for (int kh = 0; kh < 2; kh++) {
            aoff[e][kh] = (size_t)(m0 + row) * D_DIM + (size_t)(kh * 4 + ((U & 3) ^ ((row >> 1) & 3))) * 8;
            alds[e][kh] = kh * 8192 + (wave * 2 + e) * 512;
        }
    }
    size_t boff[2]; int blds[2];
    {
        const int U = wave * 64 + lane;
        const int row = U >> 2;
#pragma unroll
        for (int kh = 0; kh < 2; kh++) {
            boff[kh] = (size_t)(n0 + row) * D_DIM + (size_t)(kh * 4 + ((U & 3) ^ ((row >> 1) & 3))) * 8;
            blds[kh] = kh * 4096 + wave * 512;
        }
    }

#define STAGE_A(Abuf, KH, kb) do {                                                        \
    async_copy16((void*)((Abuf) + alds[0][KH]), (const void*)(XH + aoff[0][KH] + (kb)));  \
    async_copy16((void*)((Abuf) + alds[1][KH]), (const void*)(XH + aoff[1][KH] + (kb)));  \
} while (0)
#define STAGE_BH(Bbuf, KH, kb) async_copy16((void*)((Bbuf) + blds[KH]), (const void*)(CH + boff[KH] + (kb)))
#define STAGE_BL(Bbuf, KH, kb) async_copy16((void*)((Bbuf) + blds[KH]), (const void*)(CL + boff[KH] + (kb)))

#define PH_MFMA() do {                                                                    \
    __builtin_amdgcn_s_barrier();                                                         \
    asm volatile("s_waitcnt lgkmcnt(0)" ::: "memory");                                    \
    __builtin_amdgcn_sched_barrier(0);                                                    \
    __builtin_amdgcn_s_setprio(1);                                                        \
    _Pragma("unroll")                                                                     \
    for (int mi = 0; mi < 4; mi++) {                                                      \
        _Pragma("unroll")                                                                 \
        for (int ni = 0; ni < 4; ni++)                                                    \
            acc[mi][ni] = __builtin_amdgcn_mfma_f32_16x16x32_f16(a[mi], b[ni], acc[mi][ni], 0, 0, 0); \
    }                                                                                     \
    __builtin_amdgcn_s_setprio(0);                                                        \
    __builtin_amdgcn_s_barrier();                                                         \
} while (0)

    f32x4 acc[4][4];
#pragma unroll
    for (int mi = 0; mi < 4; mi++)
#pragma unroll
        for (int ni = 0; ni < 4; ni++) {
            acc[mi][ni].x = 0.f; acc[mi][ni].y = 0.f;
            acc[mi][ni].z = 0.f; acc[mi][ni].w = 0.f;
        }

    f16x8 a[4], b[4];

    // ---- prologue: stage tile 0 (chunks c0..c3 in vmcnt FIFO order) ----
    STAGE_A(A0, 0, 0); STAGE_BH(Bh0, 0, 0);   // c0 (3 loads/thread)
    STAGE_BL(Bl0, 0, 0);                      // c1 (1)
    STAGE_A(A0, 1, 0); STAGE_BH(Bh0, 1, 0);   // c2 (3)
    STAGE_BL(Bl0, 1, 0);                      // c3 (1)
    WAITVM(5);                                // c0 complete
    __builtin_amdgcn_s_barrier();

    // ---- steady loop: tiles 0..14 prefetch tile t+1 ----
    for (int t = 0; t < 15; t++) {
        _Float16* const Ac  = (t & 1) ? A1 : A0;
        _Float16* const Bhc = (t & 1) ? Bh1 : Bh0;
        _Float16* const Blc = (t & 1) ? Bl1 : Bl0;
        _Float16* const An  = (t & 1) ? A0 : A1;
        _Float16* const Bhn = (t & 1) ? Bh0 : Bh1;
        _Float16* const Bln = (t & 1) ? Bl0 : Bl1;
        const size_t kb = (size_t)(t + 1) * 64;

        // phase 0: A·Bh k0   (issue t+1.c0; drain t.c1 for phase 1)
        loadA4(a, Ac, wm, fr, fq, 0);
        loadB4(b, Bhc, wn, fr, fq, 0);
        STAGE_A(An, 0, kb); STAGE_BH(Bhn, 0, kb);
        WAITVM(7);
        PH_MFMA();
        // phase 1: A·Bl k0   (issue t+1.c1; drain t.c2 for phase 2)
        loadB4(b, Blc, wn, fr, fq, 0);
        STAGE_BL(Bln, 0, kb);
        WAITVM(5);
        PH_MFMA();
        // phase 2: A·Bh k1   (issue t+1.c2; drain t.c3 for phase 3)
        loadA4(a, Ac, wm, fr, fq, 1);
        loadB4(b, Bhc, wn, fr, fq, 1);
        STAGE_A(An, 1, kb); STAGE_BH(Bhn, 1, kb);
        WAITVM(7);
        PH_MFMA();
        // phase 3: A·Bl k1   (issue t+1.c3; drain t+1.c0 for next tile's phase 0)
        loadB4(b, Blc, wn, fr, fq, 1);
        STAGE_BL(Bln, 1, kb);
        WAITVM(5);
        PH_MFMA();
    }

    // ---- final tile t=15 (buffers *1, no prefetch; waits drain own chunks) ----
    loadA4(a, A1, wm, fr, fq, 0);
    loadB4(b, Bh1, wn, fr, fq, 0);
    WAITVM(4);                       // c1 done
    PH_MFMA();
    loadB4(b, Bl1, wn, fr, fq, 0);
    WAITVM(1);                       // c2 done
    PH_MFMA();
    loadA4(a, A1, wm, fr, fq, 1);
    loadB4(b, Bh1, wn, fr, fq, 1);
    WAITVM(0);                       // c3 done (only drain-to-0, once, at the end)
    PH_MFMA();
    loadB4(b, Bl1, wn, fr, fq, 1);
    __builtin_amdgcn_s_barrier();
    asm volatile("s_waitcnt lgkmcnt(0)" ::: "memory");
    __builtin_amdgcn_sched_barrier(0);
#pragma unroll
    for (int mi = 0; mi < 4; mi++)
#pragma unroll
        for (int ni = 0; ni < 4; ni++)
            acc[mi][ni] = __builtin_amdgcn_mfma_f32_16x16x32_f16(a[mi], b[ni], acc[mi][ni], 0, 0, 0);

    // ---- epilogue: C/D layout col=lane&15, row=(lane>>4)*4+reg ----
#pragma unroll
    for (int mi = 0; mi < 4; mi++)
#pragma unroll
        for (int r = 0; r < 4; r++) {
            float* dst = S + (size_t)(m0 + wm + mi * 16 + fq * 4 + r) * K_DIM + n0 + wn;
#pragma unroll
            for (int ni = 0; ni < 4; ni++) dst[ni * 16 + fr] = acc[mi][ni][r];
        }
#undef STAGE_A
#undef STAGE_BH
#undef STAGE_BL
#undef PH_MFMA
}

// ---------------------------------------------------------------------------
// Kernel 2: per-row stats. One wave per row-octet. (R2-proven version:
// scalar stride-64 S loads; sdiv atomics at stride-1 banks = conflict-free.)
// ---------------------------------------------------------------------------
#define MARGIN 0.125f
__global__ __launch_bounds__(256) void rowstats_kernel(const float* __restrict__ S,
                                                       int* __restrict__ cnt,
                                                       int* __restrict__ cand,
                                                       float* __restrict__ div_acc,
                                                       float* __restrict__ hclust_acc) {
    __shared__ float sdiv[K_DIM];
    const int tid = threadIdx.x;
    for (int k = tid; k < K_DIM; k += 256) sdiv[k] = 0.0f;
    __syncthreads();

    const int lane = tid & 63;
    const int wave = tid >> 6;

    float dreg[32];
#pragma unroll
    for (int j = 0; j < 32; j++) dreg[j] = 0.0f;
    float ent_acc = 0.0f;

    for (int r8 = 0; r8 < 8; r8++) {
        const int row = blockIdx.x * 32 + wave * 8 + r8;
        const float* srow = S + (size_t)row * K_DIM;

        float v[32];
#pragma unroll
        for (int j = 0; j < 32; j++) v[j] = srow[lane + 64 * j];

        float m = v[0];
#pragma unroll
        for (int j = 1; j < 32; j++) m = fmaxf(m, v[j]);
        for (int off = 32; off > 0; off >>= 1) m = fmaxf(m, __shfl_xor(m, off, 64));

        // candidate extraction: everything within MARGIN of the max
        const float thresh = m - MARGIN;
#pragma unroll
        for (int j = 0; j < 32; j++) {
            if (v[j] > thresh) {
                const int slot = atomicAdd(&cnt[row], 1);
                if (slot < 8) cand[row * 8 + slot] = lane + 64 * j;
            }
        }

        // softmax pieces
        float Z = 0.0f;
#pragma unroll
        for (int j = 0; j < 32; j++) {
            v[j] = __expf(v[j] - m);
            Z += v[j];
        }
        for (int off = 32; off > 0; off >>= 1) Z += __shfl_xor(Z, off, 64);
        const float invZ = 1.0f / Z;

#pragma unroll
        for (int j = 0; j < 32; j++) {
            const float p = v[j] * invZ;
            dreg[j] += p;
            ent_acc += p * __log2f(p + 1e-8f);
        }
    }

    // merge per-lane diversity into block LDS, then global
#pragma unroll
    for (int j = 0; j < 32; j++) atomicAdd(&sdiv[lane + 64 * j], dreg[j]);
    for (int off = 32; off > 0; off >>= 1) ent_acc += __shfl_xor(ent_acc, off, 64);
    if (lane == 0) atomicAdd(hclust_acc, ent_acc);
    __syncthreads();

    for (int k = tid; k < K_DIM; k += 256) atomicAdd(&div_acc[k], sdiv[k]);
}

// ---------------------------------------------------------------------------
// Kernel 2b: fp64 argmax over candidate list + fused quantize. One wave/row.
// After the reduce every lane holds the same besti, so the quantize step
// (center+normalize codebook[besti]) runs in-wave; C row is L2-hot.
// ---------------------------------------------------------------------------
__global__ __launch_bounds__(256) void refineq_kernel(const float* __restrict__ X,
                                                      const float* __restrict__ C,
                                                      const int* __restrict__ cnt,
                                                      const int* __restrict__ cand,
                                                      float* __restrict__ nn_out,
                                                      float* __restrict__ out0) {
    const int tid = threadIdx.x;
    const int lane = tid & 63;
    const int wave = tid >> 6;
    const int row = blockIdx.x * 4 + wave;

    const int n = min(cnt[row], 8);
    const float* x = X + (size_t)row * D_DIM;

    float4 xv[4];
#pragma unroll
    for (int q = 0; q < 4; q++) xv[q] = *(const float4*)(x + lane * 4 + 256 * q);

    double bestv = -1.0e300;
    int besti = 0x7fffffff;
    for (int c = 0; c < n; c++) {
        const int idx = cand[row * 8 + c];
        const float* cb = C + (size_t)idx * D_DIM;
        double s = 0.0;
#pragma unroll
        for (int q = 0; q < 4; q++) {
            const float4 cv = *(const float4*)(cb + lane * 4 + 256 * q);
            s += (double)xv[q].x * cv.x + (double)xv[q].y * cv.y +
                 (double)xv[q].z * cv.z + (double)xv[q].w * cv.w;
        }
        for (int off = 32; off > 0; off >>= 1) s += __shfl_xor(s, off, 64);
        if (s > bestv || (s == bestv && idx < besti)) { bestv = s; besti = idx; }
    }
    if (lane == 0) nn_out[row] = (float)besti;

    // ---- fused quantize: normalize(center(C[besti])) ----
    const float* c = C + (size_t)besti * D_DIM;
    float4 v[4];
    float sum = 0.0f;
#pragma unroll
    for (int q = 0; q < 4; q++) {
        v[q] = *(const float4*)(c + lane * 4 + 256 * q);
        sum += v[q].x + v[q].y + v[q].z + v[q].w;
    }
    for (int off = 32; off > 0; off >>= 1) sum += __shfl_xor(sum, off, 64);
    const float mean = sum * (1.0f / 1024.0f);

    float ss = 0.0f;
#pragma unroll
    for (int q = 0; q < 4; q++) {
        v[q].x -= mean; v[q].y -= mean; v[q].z -= mean; v[q].w -= mean;
        ss += v[q].x * v[q].x + v[q].y * v[q].y + v[q].z * v[q].z + v[q].w * v[q].w;
    }
    for (int off = 32; off > 0; off >>= 1) ss += __shfl_xor(ss, off, 64);
    const float inv = 1.0f / sqrtf(ss);

    float* o = out0 + (size_t)row * D_DIM;
#pragma unroll
    for (int q = 0; q < 4; q++) {
        float4 w = v[q];
        w.x *= inv; w.y *= inv; w.z *= inv; w.w *= inv;
        *(float4*)(o + lane * 4 + 256 * q) = w;
    }
}

// ---------------------------------------------------------------------------
// Kernel 3: finalize scalar loss = h_clust - GAMMA * h_diversity
// ---------------------------------------------------------------------------
__global__ __launch_bounds__(256) void finalize_kernel(const float* __restrict__ div_acc,
                                                       const float* __restrict__ hclust_acc,
                                                       float* __restrict__ loss_out) {
    __shared__ float red[256];
    const int tid = threadIdx.x;
    float sum = 0.0f;
    for (int k = tid; k < K_DIM; k += 256) {
        const float d = div_acc[k] * (1.0f / 32768.0f);
        sum += d * __log2f(d + 1e-8f);
    }
    red[tid] = sum;
    __syncthreads();
    for (int s = 128; s > 0; s >>= 1) {
        if (tid < s) red[tid] += red[tid + s];
        __syncthreads();
    }
    if (tid == 0) {
        const float h_clust = -hclust_acc[0] * (1.0f / 32768.0f);
        const float h_div = -red[0];
        loss_out[0] = h_clust - 1.0f * h_div;   // GAMMA = 1
    }
}

// ---------------------------------------------------------------------------
// Kernel 4: broadcast loss scalar into out1 region (67,108,864 floats)
// ---------------------------------------------------------------------------
__global__ __launch_bounds__(256) void fill_kernel(float* __restrict__ out1,
                                                   const float* __restrict__ loss_ptr) {
    const float v = loss_ptr[0];
    const float4 f = make_float4(v, v, v, v);
    float4* o = (float4*)out1;
    const size_t stride = (size_t)gridDim.x * blockDim.x;
    for (size_t i = (size_t)blockIdx.x * blockDim.x + threadIdx.x; i < 16777216ULL; i += stride)
        o[i] = f;
}

// ---------------------------------------------------------------------------
// Kernel 6: codebook passthrough copy (runs LAST: out3 region holds scratch
// cand/cnt/div until then)
// ---------------------------------------------------------------------------
__global__ __launch_bounds__(256) void copycb_kernel(const float* __restrict__ C,
                                                     float* __restrict__ out3) {
    const size_t i = (size_t)blockIdx.x * 256 + threadIdx.x;
    if (i < 524288ULL) ((float4*)out3)[i] = ((const float4*)C)[i];
}

// ---------------------------------------------------------------------------
extern "C" void kernel_launch(void* const* d_in, const int* in_sizes, int n_in,
                              void* d_out, int out_size, void* d_ws, size_t ws_size,
                              hipStream_t stream) {
    const float* X = (const float*)d_in[0];   // [16,2048,1024]
    const float* C = (const float*)d_in[1];   // [2048,1024]
    float* out = (float*)d_out;

    // fp16 operand scratch in the out0 region (free until refineq writes out0)
    char* scratch = (char*)d_out;
    _Float16* CH  = (_Float16*)(scratch);                 // 4 MB
    _Float16* CL  = (_Float16*)(scratch + (4 << 20));     // 4 MB
    _Float16* XH  = (_Float16*)(scratch + (16 << 20));    // 64 MB  [32768][1024] fp16

    // cand/cnt/div scratch in the out3 region (free until tail copycb;
    // survives refineq's out0 writes)
    char* s3 = (char*)(out + OUT3_OFF);
    int* cand      = (int*)s3;                            // 1 MB   [32768][8]
    int* cnt       = (int*)(s3 + (1 << 20));              // 128 KB
    float* div_acc = (float*)(s3 + (1 << 20) + (128 << 10));  // 8 KB
    float* hclust  = div_acc + 2048;
    float* loss    = div_acc + 2049;

    float* S = out + OUT1_OFF;                // similarity scratch in out1 region

    // zero cnt + div + hclust + loss (contiguous)
    hipMemsetAsync(s3 + (1 << 20), 0, (128 << 10) + 8192 + 16, stream);

    // 0) codebook fp16 split
    convcb_kernel<<<2048, 256, 0, stream>>>(C, CH, CL);

    // 0b) X fp16 convert
    convx_kernel<<<32768, 256, 0, stream>>>(X, XH);

    // 1) S = xh·ch + xh·cl  (8-phase counted-vmcnt MFMA GEMM)
    gemm_kernel<<<2048, 512, 0, stream>>>(XH, CH, CL, S);

    // 2) per-row stats -> candidates, diversity, entropy sum
    rowstats_kernel<<<M_TOTAL / 32, 256, 0, stream>>>(S, cnt, cand, div_acc, hclust);

    // 2b) fp64 argmax refinement + fused quantize -> nn_idx, out0
    refineq_kernel<<<M_TOTAL / 4, 256, 0, stream>>>(X, C, cnt, cand,
                                                    out + OUT2_OFF, out + OUT0_OFF);

    // 3) scalar loss
    finalize_kernel<<<1, 256, 0, stream>>>(div_acc, hclust, loss);

    // 4) broadcast loss over out1 (overwrites S scratch)
    fill_kernel<<<8192, 256, 0, stream>>>(out + OUT1_OFF, loss);

    // 6) codebook copy (the real out3 payload, last)
    copycb_kernel<<<2048, 256, 0, stream>>>(C, out + OUT3_OFF);
}

// Round 5
// 913.250 us; speedup vs baseline: 1.1497x; 1.0422x over previous
//
#include <hip/hip_runtime.h>
#include <math.h>

// Problem constants
#define M_TOTAL 32768   // B*T = 16*2048
#define D_DIM   1024
#define K_DIM   2048

// d_out flat layout (float32 elements)
#define OUT0_OFF 0ULL           // quantized   [32768,1024]  (scratch until statsref)
#define OUT1_OFF 33554432ULL    // quant_loss  [32768,2048] (S scratch, then loss fill)
#define OUT2_OFF 100663296ULL   // nn_idx      [32768] (written as float)
#define OUT3_OFF 100696064ULL   // codebook    [2048,1024] (div scratch until tail copy)

typedef _Float16 f16x4 __attribute__((ext_vector_type(4)));
typedef _Float16 f16x8 __attribute__((ext_vector_type(8)));
typedef float    f32x4 __attribute__((ext_vector_type(4)));

#define STR_(x) #x
#define STR(x) STR_(x)
#define WAITVM(N) asm volatile("s_waitcnt vmcnt(" STR(N) ")" ::: "memory")

// ---------------------------------------------------------------------------
// async 16B global -> LDS (wave-uniform LDS base + lane*16)
// ---------------------------------------------------------------------------
__device__ __forceinline__ void async_copy16(void* lds, const void* g) {
    __builtin_amdgcn_global_load_lds(
        (const __attribute__((address_space(1))) unsigned int*)g,
        (__attribute__((address_space(3))) unsigned int*)lds, 16, 0, 0);
}

// ---------------------------------------------------------------------------
// Kernel 0: codebook fp32 -> (ch, cl) fp16 split.  c = ch + cl + O(2^-22)
// ---------------------------------------------------------------------------
__global__ __launch_bounds__(256) void convcb_kernel(const float* __restrict__ C,
                                                     _Float16* __restrict__ ch,
                                                     _Float16* __restrict__ cl) {
    const int i = blockIdx.x * 256 + threadIdx.x;   // float4 index, 524288 total
    const float4 c = ((const float4*)C)[i];
    f16x4 h, l;
    h.x = (_Float16)c.x; l.x = (_Float16)(c.x - (float)h.x);
    h.y = (_Float16)c.y; l.y = (_Float16)(c.y - (float)h.y);
    h.z = (_Float16)c.z; l.z = (_Float16)(c.z - (float)h.z);
    h.w = (_Float16)c.w; l.w = (_Float16)(c.w - (float)h.w);
    ((f16x4*)ch)[i] = h;
    ((f16x4*)cl)[i] = l;
}

// ---------------------------------------------------------------------------
// Kernel 0b: X fp32 -> fp16 (high part only; verified numerics)
// ---------------------------------------------------------------------------
__global__ __launch_bounds__(256) void convx_kernel(const float* __restrict__ X,
                                                    _Float16* __restrict__ xh) {
    const size_t i = (size_t)blockIdx.x * 256 + threadIdx.x;  // float4 idx, 8388608
    const float4 a = ((const float4*)X)[i];
    f16x4 h;
    h.x = (_Float16)a.x; h.y = (_Float16)a.y;
    h.z = (_Float16)a.z; h.w = (_Float16)a.w;
    ((f16x4*)xh)[i] = h;
}

// ---------------------------------------------------------------------------
// Kernel 1: MFMA GEMM  S[m][n] = xh[m]·ch[n] + xh[m]·cl[n]
// 2-phase counted-vmcnt schedule (T3+T4+T5, barrier-amortized):
//   tile 256x128, BK=64, 8 waves (4M x 2N, each 64x64), LDS 128KB dbuf.
//   2 phases per K-tile, 32 MFMA each (vs R4's 4x16: halves barrier count):
//     phase0: ds_read A(kh0,kh1)+Bh(kh0,kh1) [16 b128]; stage c0(t+1) [6 ld];
//             WAITVM(6) (drains c1(t)); barrier; 32 MFMA A·Bh; barrier.
//     phase1: ds_read Bl(kh0,kh1) [8 b128], A-frags REUSED from phase0;
//             stage c1(t+1) [2 ld]; WAITVM(2) (drains c0(t+1)); barrier;
//             32 MFMA A·Bl; barrier.
//   Never vmcnt(0) in the steady loop. Raw s_barrier, not __syncthreads.
// LDS layout per operand: [kh][row][4 units of 16B], unit XOR fq^((row>>1)&3)
//   (R4-verified conflict-free: covers all 8 bank-groups exactly twice for a
//   quarter-wave b128 read). global_load_lds writes linearly; the global
//   source address carries the permutation (involution both sides).
// ---------------------------------------------------------------------------
__device__ __forceinline__ void loadA8(f16x8* a, const _Float16* Ab, int wm, int fr, int fq) {
#pragma unroll
    for (int kh = 0; kh < 2; kh++)
#pragma unroll
        for (int mi = 0; mi < 4; mi++) {
            const int row = wm + mi * 16 + fr;
            a[kh * 4 + mi] = *(const f16x8*)(Ab + kh * 8192 + row * 32 + (fq ^ ((row >> 1) & 3)) * 8);
        }
}
__device__ __forceinline__ void loadB8(f16x8* b, const _Float16* Bb, int wn, int fr, int fq) {
#pragma unroll
    for (int kh = 0; kh < 2; kh++)
#pragma unroll
        for (int ni = 0; ni < 4; ni++) {
            const int row = wn + ni * 16 + fr;
            b[kh * 4 + ni] = *(const f16x8*)(Bb + kh * 4096 + row * 32 + (fq ^ ((row >> 1) & 3)) * 8);
        }
}

__global__ __launch_bounds__(512, 2) void gemm_kernel(const _Float16* __restrict__ XH,
                                                      const _Float16* __restrict__ CH,
                                                      const _Float16* __restrict__ CL,
                                                      float* __restrict__ S) {
    __shared__ _Float16 lds[65536];      // 128 KB
    _Float16* const A0  = lds;           // [2][256][32]  (kh-major)
    _Float16* const Bh0 = lds + 16384;   // [2][128][32]
    _Float16* const Bl0 = lds + 24576;
    _Float16* const A1  = lds + 32768;
    _Float16* const Bh1 = lds + 49152;
    _Float16* const Bl1 = lds + 57344;

    const int tid  = threadIdx.x;
    const int lane = tid & 63;
    const int wave = tid >> 6;

    // XCD-grouped mapping: xcd x owns m-blocks [x*16, x*16+16) x all 16 n-blocks
    const int bq  = blockIdx.x;
    const int xcd = bq & 7;
    const int idx = bq >> 3;
    const int m0 = (xcd * 16 + (idx >> 4)) * 256;
    const int n0 = (idx & 15) * 128;

    const int wm = (wave & 3) * 64;      // 4 M-waves
    const int wn = (wave >> 2) * 64;     // 2 N-waves
    const int fr = lane & 15;
    const int fq = lane >> 4;

    // ---- staging constants (per-thread, hoisted out of the K loop) ----
    size_t aoff[2][2]; int alds[2][2];
#pragma unroll
    for (int e = 0; e < 2; e++) {
        const int U = (wave * 2 + e) * 64 + lane;
        const int row = U >> 2;
#pragma unroll
        for (int kh = 0; kh < 2; kh++) {
            aoff[e][kh] = (size_t)(m0 + row) * D_DIM + (size_t)(kh * 4 + ((U & 3) ^ ((row >> 1) & 3))) * 8;
            alds[e][kh] = kh * 8192 + (wave * 2 + e) * 512;
        }
    }
    size_t boff[2]; int blds[2];
    {
        const int U = wave * 64 + lane;
        const int row = U >> 2;
#pragma unroll
        for (int kh = 0; kh < 2; kh++) {
            boff[kh] = (size_t)(n0 + row) * D_DIM + (size_t)(kh * 4 + ((U & 3) ^ ((row >> 1) & 3))) * 8;
            blds[kh] = kh * 4096 + wave * 512;
        }
    }

// c0 chunk: A both kh (4 ld/thr) + Bh both kh (2 ld/thr) = 6
#define STAGE_C0(Abuf, Bbuf, kb) do {                                                       \
    async_copy16((void*)((Abuf) + alds[0][0]), (const void*)(XH + aoff[0][0] + (kb)));      \
    async_copy16((void*)((Abuf) + alds[1][0]), (const void*)(XH + aoff[1][0] + (kb)));      \
    async_copy16((void*)((Abuf) + alds[0][1]), (const void*)(XH + aoff[0][1] + (kb)));      \
    async_copy16((void*)((Abuf) + alds[1][1]), (const void*)(XH + aoff[1][1] + (kb)));      \
    async_copy16((void*)((Bbuf) + blds[0]),    (const void*)(CH + boff[0] + (kb)));         \
    async_copy16((void*)((Bbuf) + blds[1]),    (const void*)(CH + boff[1] + (kb)));         \
} while (0)
// c1 chunk: Bl both kh = 2
#define STAGE_C1(Bbuf, kb) do {                                                             \
    async_copy16((void*)((Bbuf) + blds[0]),    (const void*)(CL + boff[0] + (kb)));         \
    async_copy16((void*)((Bbuf) + blds[1]),    (const void*)(CL + boff[1] + (kb)));         \
} while (0)

#define PH32() do {                                                                         \
    __builtin_amdgcn_s_barrier();                                                           \
    asm volatile("s_waitcnt lgkmcnt(0)" ::: "memory");                                      \
    __builtin_amdgcn_sched_barrier(0);                                                      \
    __builtin_amdgcn_s_setprio(1);                                                          \
    _Pragma("unroll")                                                                       \
    for (int kh = 0; kh < 2; kh++) {                                                        \
        _Pragma("unroll")                                                                   \
        for (int mi = 0; mi < 4; mi++) {                                                    \
            _Pragma("unroll")                                                               \
            for (int ni = 0; ni < 4; ni++)                                                  \
                acc[mi][ni] = __builtin_amdgcn_mfma_f32_16x16x32_f16(a[kh * 4 + mi], b[kh * 4 + ni], acc[mi][ni], 0, 0, 0); \
        }                                                                                   \
    }                                                                                       \
    __builtin_amdgcn_s_setprio(0);                                                          \
    __builtin_amdgcn_s_barrier();                                                           \
} while (0)

    f32x4 acc[4][4];
#pragma unroll
    for (int mi = 0; mi < 4; mi++)
#pragma unroll
        for (int ni = 0; ni < 4; ni++) {
            acc[mi][ni].x = 0.f; acc[mi][ni].y = 0.f;
            acc[mi][ni].z = 0.f; acc[mi][ni].w = 0.f;
        }

    f16x8 a[8], b[8];

    // ---- prologue: stage tile 0 (c0 then c1 in vmcnt FIFO order) ----
    STAGE_C0(A0, Bh0, 0);            // 6 loads
    STAGE_C1(Bl0, 0);                // 2 loads
    WAITVM(2);                       // c0 complete
    __builtin_amdgcn_s_barrier();

    // ---- steady loop: tiles 0..14 prefetch tile t+1 ----
    for (int t = 0; t < 15; t++) {
        _Float16* const Ac  = (t & 1) ? A1 : A0;
        _Float16* const Bhc = (t & 1) ? Bh1 : Bh0;
        _Float16* const Blc = (t & 1) ? Bl1 : Bl0;
        _Float16* const An  = (t & 1) ? A0 : A1;
        _Float16* const Bhn = (t & 1) ? Bh0 : Bh1;
        _Float16* const Bln = (t & 1) ? Bl0 : Bl1;
        const size_t kb = (size_t)(t + 1) * 64;

        // phase 0: A·Bh (both kh)   (issue t+1.c0; drain t.c1 for phase 1)
        loadA8(a, Ac, wm, fr, fq);
        loadB8(b, Bhc, wn, fr, fq);
        STAGE_C0(An, Bhn, kb);
        WAITVM(6);
        PH32();
        // phase 1: A·Bl (both kh), A-frags reused (issue t+1.c1; drain t+1.c0)
        loadB8(b, Blc, wn, fr, fq);
        STAGE_C1(Bln, kb);
        WAITVM(2);
        PH32();
    }

    // ---- final tile t=15 (buffers *1, no prefetch) ----
    loadA8(a, A1, wm, fr, fq);
    loadB8(b, Bh1, wn, fr, fq);
    WAITVM(0);                       // c1(15) done (only drain-to-0, at the end)
    PH32();
    loadB8(b, Bl1, wn, fr, fq);
    asm volatile("s_waitcnt lgkmcnt(0)" ::: "memory");
    __builtin_amdgcn_sched_barrier(0);
#pragma unroll
    for (int kh = 0; kh < 2; kh++)
#pragma unroll
        for (int mi = 0; mi < 4; mi++)
#pragma unroll
            for (int ni = 0; ni < 4; ni++)
                acc[mi][ni] = __builtin_amdgcn_mfma_f32_16x16x32_f16(a[kh * 4 + mi], b[kh * 4 + ni], acc[mi][ni], 0, 0, 0);

    // ---- epilogue: C/D layout col=lane&15, row=(lane>>4)*4+reg ----
#pragma unroll
    for (int mi = 0; mi < 4; mi++)
#pragma unroll
        for (int r = 0; r < 4; r++) {
            float* dst = S + (size_t)(m0 + wm + mi * 16 + fq * 4 + r) * K_DIM + n0 + wn;
#pragma unroll
            for (int ni = 0; ni < 4; ni++) dst[ni * 16 + fr] = acc[mi][ni][r];
        }
#undef STAGE_C0
#undef STAGE_C1
#undef PH32
}

// ---------------------------------------------------------------------------
// Kernel 2: fused per-row stats + fp64 argmax refine + quantize.
// One block per 32 rows (4 waves x 8 rows). Stats inner loop is the
// R2-proven version. Candidates stay in LDS (wave-local: each wave refines
// its own rows), eliminating the global cand/cnt round-trip and one launch.
// ---------------------------------------------------------------------------
#define MARGIN 0.125f
__global__ __launch_bounds__(256) void statsref_kernel(const float* __restrict__ S,
                                                       const float* __restrict__ X,
                                                       const float* __restrict__ C,
                                                       float* __restrict__ div_acc,
                                                       float* __restrict__ hclust_acc,
                                                       float* __restrict__ nn_out,
                                                       float* __restrict__ out0) {
    __shared__ float sdiv[K_DIM];
    __shared__ int scnt[32];
    __shared__ int scand[32][8];
    const int tid = threadIdx.x;
    for (int k = tid; k < K_DIM; k += 256) sdiv[k] = 0.0f;
    if (tid < 32) scnt[tid] = 0;
    __syncthreads();

    const int lane = tid & 63;
    const int wave = tid >> 6;

    float dreg[32];
#pragma unroll
    for (int j = 0; j < 32; j++) dreg[j] = 0.0f;
    float ent_acc = 0.0f;

    for (int r8 = 0; r8 < 8; r8++) {
        const int lr = wave * 8 + r8;
        const int row = blockIdx.x * 32 + lr;
        const float* srow = S + (size_t)row * K_DIM;

        float v[32];
#pragma unroll
        for (int j = 0; j < 32; j++) v[j] = srow[lane + 64 * j];

        float m = v[0];
#pragma unroll
        for (int j = 1; j < 32; j++) m = fmaxf(m, v[j]);
        for (int off = 32; off > 0; off >>= 1) m = fmaxf(m, __shfl_xor(m, off, 64));

        // candidate extraction: everything within MARGIN of the max
        const float thresh = m - MARGIN;
#pragma unroll
        for (int j = 0; j < 32; j++) {
            if (v[j] > thresh) {
                const int slot = atomicAdd(&scnt[lr], 1);
                if (slot < 8) scand[lr][slot] = lane + 64 * j;
            }
        }

        // softmax pieces
        float Z = 0.0f;
#pragma unroll
        for (int j = 0; j < 32; j++) {
            v[j] = __expf(v[j] - m);
            Z += v[j];
        }
        for (int off = 32; off > 0; off >>= 1) Z += __shfl_xor(Z, off, 64);
        const float invZ = 1.0f / Z;

#pragma unroll
        for (int j = 0; j < 32; j++) {
            const float p = v[j] * invZ;
            dreg[j] += p;
            ent_acc += p * __log2f(p + 1e-8f);
        }
    }

    // merge per-lane diversity into block LDS, then global
#pragma unroll
    for (int j = 0; j < 32; j++) atomicAdd(&sdiv[lane + 64 * j], dreg[j]);
    for (int off = 32; off > 0; off >>= 1) ent_acc += __shfl_xor(ent_acc, off, 64);
    if (lane == 0) atomicAdd(hclust_acc, ent_acc);
    __syncthreads();

    for (int k = tid; k < K_DIM; k += 256) atomicAdd(&div_acc[k], sdiv[k]);

    // ---- refine + quantize phase (wave-local candidates, no extra sync) ----
    for (int r8 = 0; r8 < 8; r8++) {
        const int lr = wave * 8 + r8;
        const int row = blockIdx.x * 32 + lr;
        const int n = min(scnt[lr], 8);
        const float* x = X + (size_t)row * D_DIM;

        float4 xv[4];
#pragma unroll
        for (int q = 0; q < 4; q++) xv[q] = *(const float4*)(x + lane * 4 + 256 * q);

        double bestv = -1.0e300;
        int besti = 0x7fffffff;
        for (int c = 0; c < n; c++) {
            const int cidx = scand[lr][c];
            const float* cb = C + (size_t)cidx * D_DIM;
            double s = 0.0;
#pragma unroll
            for (int q = 0; q < 4; q++) {
                const float4 cv = *(const float4*)(cb + lane * 4 + 256 * q);
                s += (double)xv[q].x * cv.x + (double)xv[q].y * cv.y +
                     (double)xv[q].z * cv.z + (double)xv[q].w * cv.w;
            }
            for (int off = 32; off > 0; off >>= 1) s += __shfl_xor(s, off, 64);
            if (s > bestv || (s == bestv && cidx < besti)) { bestv = s; besti = cidx; }
        }
        if (lane == 0) nn_out[row] = (float)besti;

        // quantize: normalize(center(C[besti]))
        const float* c = C + (size_t)besti * D_DIM;
        float4 v[4];
        float sum = 0.0f;
#pragma unroll
        for (int q = 0; q < 4; q++) {
            v[q] = *(const float4*)(c + lane * 4 + 256 * q);
            sum += v[q].x + v[q].y + v[q].z + v[q].w;
        }
        for (int off = 32; off > 0; off >>= 1) sum += __shfl_xor(sum, off, 64);
        const float mean = sum * (1.0f / 1024.0f);

        float ss = 0.0f;
#pragma unroll
        for (int q = 0; q < 4; q++) {
            v[q].x -= mean; v[q].y -= mean; v[q].z -= mean; v[q].w -= mean;
            ss += v[q].x * v[q].x + v[q].y * v[q].y + v[q].z * v[q].z + v[q].w * v[q].w;
        }
        for (int off = 32; off > 0; off >>= 1) ss += __shfl_xor(ss, off, 64);
        const float inv = 1.0f / sqrtf(ss);

        float* o = out0 + (size_t)row * D_DIM;
#pragma unroll
        for (int q = 0; q < 4; q++) {
            float4 w = v[q];
            w.x *= inv; w.y *= inv; w.z *= inv; w.w *= inv;
            *(float4*)(o + lane * 4 + 256 * q) = w;
        }
    }
}

// ---------------------------------------------------------------------------
// Kernel 3: finalize scalar loss = h_clust - GAMMA * h_diversity
// ---------------------------------------------------------------------------
__global__ __launch_bounds__(256) void finalize_kernel(const float* __restrict__ div_acc,
                                                       const float* __restrict__ hclust_acc,
                                                       float* __restrict__ loss_out) {
    __shared__ float red[256];
    const int tid = threadIdx.x;
    float sum = 0.0f;
    for (int k = tid; k < K_DIM; k += 256) {
        const float d = div_acc[k] * (1.0f / 32768.0f);
        sum += d * __log2f(d + 1e-8f);
    }
    red[tid] = sum;
    __syncthreads();
    for (int s = 128; s > 0; s >>= 1) {
        if (tid < s) red[tid] += red[tid + s];
        __syncthreads();
    }
    if (tid == 0) {
        const float h_clust = -hclust_acc[0] * (1.0f / 32768.0f);
        const float h_div = -red[0];
        loss_out[0] = h_clust - 1.0f * h_div;   // GAMMA = 1
    }
}

// ---------------------------------------------------------------------------
// Kernel 4: broadcast loss scalar into out1 region (67,108,864 floats)
// ---------------------------------------------------------------------------
__global__ __launch_bounds__(256) void fill_kernel(float* __restrict__ out1,
                                                   const float* __restrict__ loss_ptr) {
    const float v = loss_ptr[0];
    const float4 f = make_float4(v, v, v, v);
    float4* o = (float4*)out1;
    const size_t stride = (size_t)gridDim.x * blockDim.x;
    for (size_t i = (size_t)blockIdx.x * blockDim.x + threadIdx.x; i < 16777216ULL; i += stride)
        o[i] = f;
}

// ---------------------------------------------------------------------------
// Kernel 6: codebook passthrough copy (runs LAST: out3 region holds scratch
// div/hclust/loss until finalize has consumed them)
// ---------------------------------------------------------------------------
__global__ __launch_bounds__(256) void copycb_kernel(const float* __restrict__ C,
                                                     float* __restrict__ out3) {
    const size_t i = (size_t)blockIdx.x * 256 + threadIdx.x;
    if (i < 524288ULL) ((float4*)out3)[i] = ((const float4*)C)[i];
}

// ---------------------------------------------------------------------------
extern "C" void kernel_launch(void* const* d_in, const int* in_sizes, int n_in,
                              void* d_out, int out_size, void* d_ws, size_t ws_size,
                              hipStream_t stream) {
    const float* X = (const float*)d_in[0];   // [16,2048,1024]
    const float* C = (const float*)d_in[1];   // [2048,1024]
    float* out = (float*)d_out;

    // fp16 operand scratch in the out0 region (free until statsref writes out0)
    char* scratch = (char*)d_out;
    _Float16* CH  = (_Float16*)(scratch);                 // 4 MB
    _Float16* CL  = (_Float16*)(scratch + (4 << 20));     // 4 MB
    _Float16* XH  = (_Float16*)(scratch + (16 << 20));    // 64 MB  [32768][1024] fp16

    // div/hclust/loss scratch in the out3 region (free until tail copycb)
    char* s3 = (char*)(out + OUT3_OFF);
    float* div_acc = (float*)s3;                          // 8 KB
    float* hclust  = div_acc + 2048;
    float* loss    = div_acc + 2049;

    float* S = out + OUT1_OFF;                // similarity scratch in out1 region

    // zero div + hclust + loss (contiguous, 8.2 KB)
    hipMemsetAsync(s3, 0, 8192 + 16, stream);

    // 0) codebook fp16 split
    convcb_kernel<<<2048, 256, 0, stream>>>(C, CH, CL);

    // 0b) X fp16 convert
    convx_kernel<<<32768, 256, 0, stream>>>(X, XH);

    // 1) S = xh·ch + xh·cl  (2-phase counted-vmcnt MFMA GEMM)
    gemm_kernel<<<2048, 512, 0, stream>>>(XH, CH, CL, S);

    // 2) fused stats + refine + quantize -> div/hclust, nn_idx, out0
    statsref_kernel<<<M_TOTAL / 32, 256, 0, stream>>>(S, X, C, div_acc, hclust,
                                                      out + OUT2_OFF, out + OUT0_OFF);

    // 3) scalar loss
    finalize_kernel<<<1, 256, 0, stream>>>(div_acc, hclust, loss);

    // 4) broadcast loss over out1 (overwrites S scratch)
    fill_kernel<<<8192, 256, 0, stream>>>(out + OUT1_OFF, loss);

    // 6) codebook copy (the real out3 payload, last)
    copycb_kernel<<<2048, 256, 0, stream>>>(C, out + OUT3_OFF);
}

// Round 7
// 867.395 us; speedup vs baseline: 1.2104x; 1.0529x over previous
//
#include <hip/hip_runtime.h>
#include <math.h>

// Problem constants
#define M_TOTAL 32768   // B*T = 16*2048
#define D_DIM   1024
#define K_DIM   2048

// d_out flat layout (float32 elements)
#define OUT0_OFF 0ULL           // quantized   [32768,1024]  (scratch until statsref)
#define OUT1_OFF 33554432ULL    // quant_loss  [32768,2048] (S scratch, then loss fill)
#define OUT2_OFF 100663296ULL   // nn_idx      [32768] (written as float)
#define OUT3_OFF 100696064ULL   // codebook    [2048,1024] (div scratch until tail copy)

typedef _Float16 f16x4 __attribute__((ext_vector_type(4)));
typedef _Float16 f16x8 __attribute__((ext_vector_type(8)));
typedef float    f32x4 __attribute__((ext_vector_type(4)));

#define STR_(x) #x
#define STR(x) STR_(x)
#define WAITVM(N) asm volatile("s_waitcnt vmcnt(" STR(N) ")" ::: "memory")

// ---------------------------------------------------------------------------
// async 16B global -> LDS (wave-uniform LDS base + lane*16)
// ---------------------------------------------------------------------------
__device__ __forceinline__ void async_copy16(void* lds, const void* g) {
    __builtin_amdgcn_global_load_lds(
        (const __attribute__((address_space(1))) unsigned int*)g,
        (__attribute__((address_space(3))) unsigned int*)lds, 16, 0, 0);
}

// ---------------------------------------------------------------------------
// Kernel 0 (fused): codebook fp32 -> (ch, cl) fp16 split  [blocks 0..2047]
//                   X fp32 -> fp16 high part              [blocks 2048..34815]
// ---------------------------------------------------------------------------
__global__ __launch_bounds__(256) void conv_kernel(const float* __restrict__ C,
                                                   _Float16* __restrict__ ch,
                                                   _Float16* __restrict__ cl,
                                                   const float* __restrict__ X,
                                                   _Float16* __restrict__ xh) {
    if (blockIdx.x < 2048) {
        const int i = blockIdx.x * 256 + threadIdx.x;   // float4 index, 524288 total
        const float4 c = ((const float4*)C)[i];
        f16x4 h, l;
        h.x = (_Float16)c.x; l.x = (_Float16)(c.x - (float)h.x);
        h.y = (_Float16)c.y; l.y = (_Float16)(c.y - (float)h.y);
        h.z = (_Float16)c.z; l.z = (_Float16)(c.z - (float)h.z);
        h.w = (_Float16)c.w; l.w = (_Float16)(c.w - (float)h.w);
        ((f16x4*)ch)[i] = h;
        ((f16x4*)cl)[i] = l;
    } else {
        const size_t i = (size_t)(blockIdx.x - 2048) * 256 + threadIdx.x;  // 8388608
        const float4 a = ((const float4*)X)[i];
        f16x4 h;
        h.x = (_Float16)a.x; h.y = (_Float16)a.y;
        h.z = (_Float16)a.z; h.w = (_Float16)a.w;
        ((f16x4*)xh)[i] = h;
    }
}

// ---------------------------------------------------------------------------
// Kernel 1: MFMA GEMM  S[m][n] = xh[m]·ch[n] + xh[m]·cl[n]
// R4's PROVEN 4-phase counted-vmcnt pattern with the kh dim removed:
//   tile 256x128, BK=32, 8 waves (4M x 2N, each 64x64), LDS 64KB dbuf
//   -> 2 blocks/CU (vs R4/R5's 128KB = 1 block/CU). Same phase count
//   (32 tiles x 2 phases = 64), same 16 MFMA + {8,4} ds_read per phase;
//   only residency doubles so one block's MFMA hides the other's stalls.
//   Chunks: c0 = {A e0, A e1, Bh} (3 ld/thr), c1 = {Bl} (1 ld/thr).
//   Steady waits: ph0 issue c0(t+1) -> WAITVM(3) drains c1(t);
//                 ph1 issue c1(t+1) -> WAITVM(1) drains c0(t+1).
//   Never vmcnt(0) in the steady loop. Raw s_barrier, not __syncthreads.
// LDS layout per operand: [row][4 units of 16B], unit XOR fq^((row>>1)&3)
//   (R4-verified conflict-free: quarter-wave b128 group = 4*(fr&1) +
//   (fq^((fr>>1)&3)) covers all 8 bank-groups exactly twice). Linear LDS
//   dest; global source address carries the permutation (both-sides rule).
// ---------------------------------------------------------------------------
__device__ __forceinline__ void loadA4(f16x8* a, const _Float16* Ab, int wm, int fr, int fq) {
#pragma unroll
    for (int mi = 0; mi < 4; mi++) {
        const int row = wm + mi * 16 + fr;
        a[mi] = *(const f16x8*)(Ab + row * 32 + (fq ^ ((row >> 1) & 3)) * 8);
    }
}
__device__ __forceinline__ void loadB4(f16x8* b, const _Float16* Bb, int wn, int fr, int fq) {
#pragma unroll
    for (int ni = 0; ni < 4; ni++) {
        const int row = wn + ni * 16 + fr;
        b[ni] = *(const f16x8*)(Bb + row * 32 + (fq ^ ((row >> 1) & 3)) * 8);
    }
}

__global__ __launch_bounds__(512, 4) void gemm_kernel(const _Float16* __restrict__ XH,
                                                      const _Float16* __restrict__ CH,
                                                      const _Float16* __restrict__ CL,
                                                      float* __restrict__ S) {
    __shared__ _Float16 lds[32768];      // 64 KB
    _Float16* const A0  = lds;           // [256][32]
    _Float16* const Bh0 = lds + 8192;    // [128][32]
    _Float16* const Bl0 = lds + 12288;
    _Float16* const A1  = lds + 16384;
    _Float16* const Bh1 = lds + 24576;
    _Float16* const Bl1 = lds + 28672;

    const int tid  = threadIdx.x;
    const int lane = tid & 63;
    const int wave = tid >> 6;

    // XCD-grouped mapping: xcd x owns m-blocks [x*16, x*16+16) x all 16 n-blocks
    const int bq  = blockIdx.x;
    const int xcd = bq & 7;
    const int idx = bq >> 3;
    const int m0 = (xcd * 16 + (idx >> 4)) * 256;
    const int n0 = (idx & 15) * 128;

    const int wm = (wave & 3) * 64;      // 4 M-waves
    const int wn = (wave >> 2) * 64;     // 2 N-waves
    const int fr = lane & 15;
    const int fq = lane >> 4;

    // ---- staging constants (per-thread, hoisted out of the K loop) ----
    size_t aoff[2]; int alds[2];
#pragma unroll
    for (int e = 0; e < 2; e++) {
        const int U = (wave * 2 + e) * 64 + lane;   // 16B unit 0..1023
        const int row = U >> 2;
        aoff[e] = (size_t)(m0 + row) * D_DIM + (size_t)((U & 3) ^ ((row >> 1) & 3)) * 8;
        alds[e] = (wave * 2 + e) * 512;
    }
    size_t boff; int blds;
    {
        const int U = wave * 64 + lane;             // 16B unit 0..511
        const int row = U >> 2;
        boff = (size_t)(n0 + row) * D_DIM + (size_t)((U & 3) ^ ((row >> 1) & 3)) * 8;
        blds = wave * 512;
    }

// c0 chunk: A e0 + A e1 + Bh = 3 loads/thread
#define STAGE_C0(Abuf, Bbuf, kb) do {                                                   \
    async_copy16((void*)((Abuf) + alds[0]), (const void*)(XH + aoff[0] + (kb)));        \
    async_copy16((void*)((Abuf) + alds[1]), (const void*)(XH + aoff[1] + (kb)));        \
    async_copy16((void*)((Bbuf) + blds),    (const void*)(CH + boff + (kb)));           \
} while (0)
// c1 chunk: Bl = 1 load/thread
#define STAGE_C1(Bbuf, kb) \
    async_copy16((void*)((Bbuf) + blds),    (const void*)(CL + boff + (kb)))

#define PH16() do {                                                                     \
    __builtin_amdgcn_s_barrier();                                                       \
    asm volatile("s_waitcnt lgkmcnt(0)" ::: "memory");                                  \
    __builtin_amdgcn_sched_barrier(0);                                                  \
    __builtin_amdgcn_s_setprio(1);                                                      \
    _Pragma("unroll")                                                                   \
    for (int mi = 0; mi < 4; mi++) {                                                    \
        _Pragma("unroll")                                                               \
        for (int ni = 0; ni < 4; ni++)                                                  \
            acc[mi][ni] = __builtin_amdgcn_mfma_f32_16x16x32_f16(a[mi], b[ni], acc[mi][ni], 0, 0, 0); \
    }                                                                                   \
    __builtin_amdgcn_s_setprio(0);                                                      \
    __builtin_amdgcn_s_barrier();                                                       \
} while (0)

    f32x4 acc[4][4];
#pragma unroll
    for (int mi = 0; mi < 4; mi++)
#pragma unroll
        for (int ni = 0; ni < 4; ni++) {
            acc[mi][ni].x = 0.f; acc[mi][ni].y = 0.f;
            acc[mi][ni].z = 0.f; acc[mi][ni].w = 0.f;
        }

    f16x8 a[4], b[4];

    // ---- prologue: stage tile 0 (c0 then c1 in vmcnt FIFO order) ----
    STAGE_C0(A0, Bh0, 0);            // 3 loads
    STAGE_C1(Bl0, 0);                // 1 load
    WAITVM(1);                       // c0 complete
    __builtin_amdgcn_s_barrier();

    // ---- steady loop: tiles 0..30 prefetch tile t+1 ----
    for (int t = 0; t < 31; t++) {
        _Float16* const Ac  = (t & 1) ? A1 : A0;
        _Float16* const Bhc = (t & 1) ? Bh1 : Bh0;
        _Float16* const Blc = (t & 1) ? Bl1 : Bl0;
        _Float16* const An  = (t & 1) ? A0 : A1;
        _Float16* const Bhn = (t & 1) ? Bh0 : Bh1;
        _Float16* const Bln = (t & 1) ? Bl0 : Bl1;
        const size_t kb = (size_t)(t + 1) * 32;

        // phase 0: A·Bh   (issue t+1.c0; drain t.c1 for phase 1)
        loadA4(a, Ac, wm, fr, fq);
        loadB4(b, Bhc, wn, fr, fq);
        STAGE_C0(An, Bhn, kb);
        WAITVM(3);
        PH16();
        // phase 1: A·Bl, A-frags reused  (issue t+1.c1; drain t+1.c0)
        loadB4(b, Blc, wn, fr, fq);
        STAGE_C1(Bln, kb);
        WAITVM(1);
        PH16();
    }

    // ---- final tile t=31 (buffers *1, no prefetch) ----
    loadA4(a, A1, wm, fr, fq);
    loadB4(b, Bh1, wn, fr, fq);
    WAITVM(0);                       // c1(31) done (only drain-to-0, at the end)
    PH16();
    loadB4(b, Bl1, wn, fr, fq);
    asm volatile("s_waitcnt lgkmcnt(0)" ::: "memory");
    __builtin_amdgcn_sched_barrier(0);
#pragma unroll
    for (int mi = 0; mi < 4; mi++)
#pragma unroll
        for (int ni = 0; ni < 4; ni++)
            acc[mi][ni] = __builtin_amdgcn_mfma_f32_16x16x32_f16(a[mi], b[ni], acc[mi][ni], 0, 0, 0);

    // ---- epilogue: C/D layout col=lane&15, row=(lane>>4)*4+reg ----
#pragma unroll
    for (int mi = 0; mi < 4; mi++)
#pragma unroll
        for (int r = 0; r < 4; r++) {
            float* dst = S + (size_t)(m0 + wm + mi * 16 + fq * 4 + r) * K_DIM + n0 + wn;
#pragma unroll
            for (int ni = 0; ni < 4; ni++) dst[ni * 16 + fr] = acc[mi][ni][r];
        }
#undef STAGE_C0
#undef STAGE_C1
#undef PH16
}

// ---------------------------------------------------------------------------
// Kernel 2: fused per-row stats + fp64 argmax refine + quantize.
// One block per 32 rows (4 waves x 8 rows). Entropy via the identity
//   sum_k p*log2(p) = log2e*(E2/Z) - log2(Z),  E2 = sum e*(v-m), e=exp(v-m)
// -- removes 32 log2f per row-lane (the stats phase's transcendental half).
// Candidates stay in LDS; refine+quantize wave-local (R5-proven structure).
// ---------------------------------------------------------------------------
#define MARGIN 0.125f
__global__ __launch_bounds__(256) void statsref_kernel(const float* __restrict__ S,
                                                       const float* __restrict__ X,
                                                       const float* __restrict__ C,
                                                       float* __restrict__ div_acc,
                                                       float* __restrict__ hclust_acc,
                                                       float* __restrict__ nn_out,
                                                       float* __restrict__ out0) {
    __shared__ float sdiv[K_DIM];
    __shared__ int scnt[32];
    __shared__ int scand[32][8];
    const int tid = threadIdx.x;
    for (int k = tid; k < K_DIM; k += 256) sdiv[k] = 0.0f;
    if (tid < 32) scnt[tid] = 0;
    __syncthreads();

    const int lane = tid & 63;
    const int wave = tid >> 6;

    float dreg[32];
#pragma unroll
    for (int j = 0; j < 32; j++) dreg[j] = 0.0f;
    float ent_acc = 0.0f;   // wave-uniform per-row entropy sum

    for (int r8 = 0; r8 < 8; r8++) {
        const int lr = wave * 8 + r8;
        const int row = blockIdx.x * 32 + lr;
        const float* srow = S + (size_t)row * K_DIM;

        float v[32];
#pragma unroll
        for (int j = 0; j < 32; j++) v[j] = srow[lane + 64 * j];

        float m = v[0];
#pragma unroll
        for (int j = 1; j < 32; j++) m = fmaxf(m, v[j]);
        for (int off = 32; off > 0; off >>= 1) m = fmaxf(m, __shfl_xor(m, off, 64));

        // candidate extraction: everything within MARGIN of the max
        const float thresh = m - MARGIN;
#pragma unroll
        for (int j = 0; j < 32; j++) {
            if (v[j] > thresh) {
                const int slot = atomicAdd(&scnt[lr], 1);
                if (slot < 8) scand[lr][slot] = lane + 64 * j;
            }
        }

        // softmax pieces: Z = sum e, E2 = sum e*(v-m)
        float Z = 0.0f, E2 = 0.0f;
#pragma unroll
        for (int j = 0; j < 32; j++) {
            const float d = v[j] - m;
            const float e = __expf(d);
            v[j] = e;
            Z += e;
            E2 += e * d;
        }
        for (int off = 32; off > 0; off >>= 1) {
            Z  += __shfl_xor(Z, off, 64);
            E2 += __shfl_xor(E2, off, 64);
        }
        const float invZ = 1.0f / Z;

#pragma unroll
        for (int j = 0; j < 32; j++) dreg[j] += v[j] * invZ;
        ent_acc += 1.4426950408889634f * E2 * invZ - __log2f(Z);
    }

    // merge per-lane diversity into block LDS, then global
#pragma unroll
    for (int j = 0; j < 32; j++) atomicAdd(&sdiv[lane + 64 * j], dreg[j]);
    if (lane == 0) atomicAdd(hclust_acc, ent_acc);   // ent_acc wave-uniform
    __syncthreads();

    for (int k = tid; k < K_DIM; k += 256) atomicAdd(&div_acc[k], sdiv[k]);

    // ---- refine + quantize phase (wave-local candidates, no extra sync) ----
    for (int r8 = 0; r8 < 8; r8++) {
        const int lr = wave * 8 + r8;
        const int row = blockIdx.x * 32 + lr;
        const int n = min(scnt[lr], 8);
        const float* x = X + (size_t)row * D_DIM;

        float4 xv[4];
#pragma unroll
        for (int q = 0; q < 4; q++) xv[q] = *(const float4*)(x + lane * 4 + 256 * q);

        double bestv = -1.0e300;
        int besti = 0x7fffffff;
        for (int c = 0; c < n; c++) {
            const int cidx = scand[lr][c];
            const float* cb = C + (size_t)cidx * D_DIM;
            double s = 0.0;
#pragma unroll
            for (int q = 0; q < 4; q++) {
                const float4 cv = *(const float4*)(cb + lane * 4 + 256 * q);
                s += (double)xv[q].x * cv.x + (double)xv[q].y * cv.y +
                     (double)xv[q].z * cv.z + (double)xv[q].w * cv.w;
            }
            for (int off = 32; off > 0; off >>= 1) s += __shfl_xor(s, off, 64);
            if (s > bestv || (s == bestv && cidx < besti)) { bestv = s; besti = cidx; }
        }
        if (lane == 0) nn_out[row] = (float)besti;

        // quantize: normalize(center(C[besti]))
        const float* c = C + (size_t)besti * D_DIM;
        float4 v[4];
        float sum = 0.0f;
#pragma unroll
        for (int q = 0; q < 4; q++) {
            v[q] = *(const float4*)(c + lane * 4 + 256 * q);
            sum += v[q].x + v[q].y + v[q].z + v[q].w;
        }
        for (int off = 32; off > 0; off >>= 1) sum += __shfl_xor(sum, off, 64);
        const float mean = sum * (1.0f / 1024.0f);

        float ss = 0.0f;
#pragma unroll
        for (int q = 0; q < 4; q++) {
            v[q].x -= mean; v[q].y -= mean; v[q].z -= mean; v[q].w -= mean;
            ss += v[q].x * v[q].x + v[q].y * v[q].y + v[q].z * v[q].z + v[q].w * v[q].w;
        }
        for (int off = 32; off > 0; off >>= 1) ss += __shfl_xor(ss, off, 64);
        const float inv = 1.0f / sqrtf(ss);

        float* o = out0 + (size_t)row * D_DIM;
#pragma unroll
        for (int q = 0; q < 4; q++) {
            float4 w = v[q];
            w.x *= inv; w.y *= inv; w.z *= inv; w.w *= inv;
            *(float4*)(o + lane * 4 + 256 * q) = w;
        }
    }
}

// ---------------------------------------------------------------------------
// Kernel 3: finalize scalar loss = h_clust - GAMMA * h_diversity
// ---------------------------------------------------------------------------
__global__ __launch_bounds__(256) void finalize_kernel(const float* __restrict__ div_acc,
                                                       const float* __restrict__ hclust_acc,
                                                       float* __restrict__ loss_out) {
    __shared__ float red[256];
    const int tid = threadIdx.x;
    float sum = 0.0f;
    for (int k = tid; k < K_DIM; k += 256) {
        const float d = div_acc[k] * (1.0f / 32768.0f);
        sum += d * __log2f(d + 1e-8f);
    }
    red[tid] = sum;
    __syncthreads();
    for (int s = 128; s > 0; s >>= 1) {
        if (tid < s) red[tid] += red[tid + s];
        __syncthreads();
    }
    if (tid == 0) {
        const float h_clust = -hclust_acc[0] * (1.0f / 32768.0f);
        const float h_div = -red[0];
        loss_out[0] = h_clust - 1.0f * h_div;   // GAMMA = 1
    }
}

// ---------------------------------------------------------------------------
// Kernel 4: broadcast loss scalar into out1 region (67,108,864 floats)
// ---------------------------------------------------------------------------
__global__ __launch_bounds__(256) void fill_kernel(float* __restrict__ out1,
                                                   const float* __restrict__ loss_ptr) {
    const float v = loss_ptr[0];
    const float4 f = make_float4(v, v, v, v);
    float4* o = (float4*)out1;
    const size_t stride = (size_t)gridDim.x * blockDim.x;
    for (size_t i = (size_t)blockIdx.x * blockDim.x + threadIdx.x; i < 16777216ULL; i += stride)
        o[i] = f;
}

// ---------------------------------------------------------------------------
// Kernel 6: codebook passthrough copy (runs LAST: out3 region holds scratch
// div/hclust/loss until finalize has consumed them)
// ---------------------------------------------------------------------------
__global__ __launch_bounds__(256) void copycb_kernel(const float* __restrict__ C,
                                                     float* __restrict__ out3) {
    const size_t i = (size_t)blockIdx.x * 256 + threadIdx.x;
    if (i < 524288ULL) ((float4*)out3)[i] = ((const float4*)C)[i];
}

// ---------------------------------------------------------------------------
extern "C" void kernel_launch(void* const* d_in, const int* in_sizes, int n_in,
                              void* d_out, int out_size, void* d_ws, size_t ws_size,
                              hipStream_t stream) {
    const float* X = (const float*)d_in[0];   // [16,2048,1024]
    const float* C = (const float*)d_in[1];   // [2048,1024]
    float* out = (float*)d_out;

    // fp16 operand scratch in the out0 region (free until statsref writes out0)
    char* scratch = (char*)d_out;
    _Float16* CH  = (_Float16*)(scratch);                 // 4 MB
    _Float16* CL  = (_Float16*)(scratch + (4 << 20));     // 4 MB
    _Float16* XH  = (_Float16*)(scratch + (16 << 20));    // 64 MB  [32768][1024] fp16

    // div/hclust/loss scratch in the out3 region (free until tail copycb)
    char* s3 = (char*)(out + OUT3_OFF);
    float* div_acc = (float*)s3;                          // 8 KB
    float* hclust  = div_acc + 2048;
    float* loss    = div_acc + 2049;

    float* S = out + OUT1_OFF;                // similarity scratch in out1 region

    // zero div + hclust + loss (contiguous, 8.2 KB)
    hipMemsetAsync(s3, 0, 8192 + 16, stream);

    // 0) fused codebook fp16 split + X fp16 convert
    conv_kernel<<<34816, 256, 0, stream>>>(C, CH, CL, X, XH);

    // 1) S = xh·ch + xh·cl  (BK=32 counted-vmcnt MFMA GEMM, 2 blocks/CU)
    gemm_kernel<<<2048, 512, 0, stream>>>(XH, CH, CL, S);

    // 2) fused stats + refine + quantize -> div/hclust, nn_idx, out0
    statsref_kernel<<<M_TOTAL / 32, 256, 0, stream>>>(S, X, C, div_acc, hclust,
                                                      out + OUT2_OFF, out + OUT0_OFF);

    // 3) scalar loss
    finalize_kernel<<<1, 256, 0, stream>>>(div_acc, hclust, loss);

    // 4) broadcast loss over out1 (overwrites S scratch)
    fill_kernel<<<8192, 256, 0, stream>>>(out + OUT1_OFF, loss);

    // 6) codebook copy (the real out3 payload, last)
    copycb_kernel<<<2048, 256, 0, stream>>>(C, out + OUT3_OFF);
}